// Round 6
// baseline (220759.985 us; speedup 1.0000x reference)
//
#include <hip/hip_runtime.h>
#include <utility>

// ---------------------------------------------------------------------------
// LMUEncoder on MI355X — dtype-self-detecting round.
// Inputs are canonicalized into ws (bf16 for GEMM weights/acts, f32 for scan
// weights) based on a device-side dtype sniff of x. Naive attention + naive
// single-block scan kept from round 4 (correctness-first).
// B=8, T=1024, D_IN=80, H=512, MEM=256, L=4, NH=8, dk=64.
// ---------------------------------------------------------------------------

typedef unsigned int uint;
typedef unsigned short ushort;
typedef __attribute__((ext_vector_type(8))) short short8;
typedef __attribute__((ext_vector_type(4))) float f32x4;

#define DEVINL static __device__ __forceinline__

DEVINL float bf2f(ushort u) { uint x = ((uint)u) << 16; float f; __builtin_memcpy(&f, &x, 4); return f; }
DEVINL ushort f2bf(float f) {
    uint u; __builtin_memcpy(&u, &f, 4);
    uint r = (u + 0x7fffu + ((u >> 16) & 1u)) >> 16;
    return (ushort)r;
}

// ---------------- sizes / ws layout (bytes, 256-aligned) -------------------
#define DIN 80
#define NLAYER 4
#define ENC_SZ (8*1024*512)
#define HS_OFF ENC_SZ
#define MS_OFF (ENC_SZ + 4*8*512)
#define NEXP 257

#define OFF_B16    0u           // bf16 blob (~12.45 MB used)
#define OFF_B32    13107200u    // f32 blob (~6.3 MB used)
#define OFF_FLAG   19922944u    // 1 uint
#define OFF_A      19923200u    // 256*256 f32
#define OFF_BD     20971776u    // 256 f32
#define OFF_APRE   20972800u    // 8*1024 f32
#define OFF_ACTB   21005568u    // 8192*512 bf16 = 8388608
#define OFF_Q      29394176u    // 8192*512 bf16 (ctx aliases Q)
#define OFF_KV     37782784u    // K|V bf16 16MB; expm f64 + eo/cbuf/ys f32 alias
// total = 54560000 bytes ~ 52 MB

// ---------------- dtype sniffer --------------------------------------------
// f32 data read as ushort pairs: even-index ushorts are low-mantissa bits ->
// random exponent fields. Genuine bf16 x~N(0,1): exponent in [100,140] or 0.
__global__ __launch_bounds__(64) void k_sniff(const ushort* x, uint* flag) {
    int i = threadIdx.x;
    ushort u = x[2 * i];
    uint e = (u >> 7) & 0xffu;
    bool ok = (u == 0) || (e >= 100u && e <= 140u);
    unsigned long long m = __ballot(ok);
    if (i == 0) *flag = (m == ~0ull) ? 0u : 1u;   // 0 = bf16 inputs, 1 = f32
}

__global__ __launch_bounds__(256) void k_cvt16(const void* src, ushort* dst, int n,
                                               const uint* flag) {
    int i = blockIdx.x * 256 + threadIdx.x;
    if (i >= n) return;
    dst[i] = (*flag) ? f2bf(((const float*)src)[i]) : ((const ushort*)src)[i];
}
__global__ __launch_bounds__(256) void k_cvt32(const void* src, float* dst, int n,
                                               const uint* flag) {
    int i = blockIdx.x * 256 + threadIdx.x;
    if (i >= n) return;
    dst[i] = (*flag) ? ((const float*)src)[i] : bf2f(((const ushort*)src)[i]);
}

// ---------------- device expm (LegS, f64) ----------------------------------
// ||M||_1 = 512 -> scale 2^-11 (norm 0.25), Taylor-20 Horner, square x11.
__global__ __launch_bounds__(256) void k_expm_init(double* M, double* T) {
    int idx = blockIdx.x * 256 + threadIdx.x;
    if (idx >= NEXP * NEXP) return;
    int i = idx / NEXP, j = idx - i * NEXP;
    double v = 0.0;
    if (i < 256) {
        double R = (2.0 * i + 1.0) / 128.0;
        if (j < 256) v = ((i < j) ? -1.0 : (((i - j) & 1) ? 1.0 : -1.0)) * R;
        else         v = ((i & 1) ? -1.0 : 1.0) * R;
    }
    M[idx] = v * (1.0 / 2048.0);
    T[idx] = (i == j) ? 1.0 : 0.0;
}

__global__ __launch_bounds__(256) void k_expm_mul(const double* M, const double* src,
                                                  double* dst, int k) {
    int idx = blockIdx.x * 256 + threadIdx.x;
    if (idx >= NEXP * NEXP) return;
    int i = idx / NEXP, j = idx - i * NEXP;
    const double* a = (k ? M : src) + (size_t)i * NEXP;
    double acc = 0.0;
    for (int l = 0; l < NEXP; l++) acc += a[l] * src[(size_t)l * NEXP + j];
    dst[idx] = k ? (acc / (double)k + ((i == j) ? 1.0 : 0.0)) : acc;
}

__global__ __launch_bounds__(256) void k_expm_extract(const double* P, float* A, float* B) {
    int idx = blockIdx.x * 256 + threadIdx.x;
    if (idx >= 256 * 256) return;
    int i = idx >> 8, j = idx & 255;
    A[idx] = (float)P[(size_t)i * NEXP + j];
    if (j == 0) B[i] = (float)P[(size_t)i * NEXP + 256];
}

// ---------------- network kernels ------------------------------------------

__global__ __launch_bounds__(256) void k_in_proj(const ushort* __restrict__ x,
                                                 const ushort* __restrict__ W,
                                                 const ushort* __restrict__ bias,
                                                 ushort* __restrict__ outb) {
    int gid = blockIdx.x * 256 + threadIdx.x;
    int n = gid & 511;
    int row = gid >> 9;
    const ushort* xr = x + row * DIN;
    const ushort* wr = W + n * DIN;
    float acc = bf2f(bias[n]);
#pragma unroll
    for (int k = 0; k < DIN; k++) acc += bf2f(xr[k]) * bf2f(wr[k]);
    outb[gid] = f2bf(acc);
}

// C[M][N] = A[M][K] @ W[N][K]^T (+bias). dual!=null: write to outf/outb
// (same buffer) as f32 if *dual else bf16.
__global__ __launch_bounds__(256) void k_gemm(const ushort* A,
                                              const ushort* W,
                                              const ushort* bias,
                                              float* outf,
                                              ushort* outb,
                                              int M, int N, int K,
                                              const uint* dual) {
    int tn = blockIdx.x * 64;
    int tm = blockIdx.y * 64;
    int wave = threadIdx.x >> 6;
    int lane = threadIdx.x & 63;
    int l16 = lane & 15, q = lane >> 4;
    uint fl = dual ? *dual : 2u;
    const ushort* arow = A + (size_t)(tm + wave * 16 + l16) * K + q * 8;
    const ushort* w0 = W + (size_t)(tn + 0 + l16) * K + q * 8;
    const ushort* w1 = W + (size_t)(tn + 16 + l16) * K + q * 8;
    const ushort* w2 = W + (size_t)(tn + 32 + l16) * K + q * 8;
    const ushort* w3 = W + (size_t)(tn + 48 + l16) * K + q * 8;
    f32x4 acc[4];
#pragma unroll
    for (int j = 0; j < 4; j++) acc[j] = (f32x4){0.f, 0.f, 0.f, 0.f};
    for (int kk = 0; kk < K; kk += 32) {
        short8 a = *(const short8*)(arow + kk);
        short8 b0 = *(const short8*)(w0 + kk);
        short8 b1 = *(const short8*)(w1 + kk);
        short8 b2 = *(const short8*)(w2 + kk);
        short8 b3 = *(const short8*)(w3 + kk);
        acc[0] = __builtin_amdgcn_mfma_f32_16x16x32_bf16(a, b0, acc[0], 0, 0, 0);
        acc[1] = __builtin_amdgcn_mfma_f32_16x16x32_bf16(a, b1, acc[1], 0, 0, 0);
        acc[2] = __builtin_amdgcn_mfma_f32_16x16x32_bf16(a, b2, acc[2], 0, 0, 0);
        acc[3] = __builtin_amdgcn_mfma_f32_16x16x32_bf16(a, b3, acc[3], 0, 0, 0);
    }
#pragma unroll
    for (int j = 0; j < 4; j++) {
        int col = tn + j * 16 + l16;
        float bv = bias ? bf2f(bias[col]) : 0.f;
#pragma unroll
        for (int i = 0; i < 4; i++) {
            int m = tm + wave * 16 + q * 4 + i;
            float v = acc[j][i] + bv;
            size_t off = (size_t)m * N + col;
            if (fl == 2u) {
                if (outf) outf[off] = v;
                if (outb) outb[off] = f2bf(v);
            } else if (fl == 1u) {
                outf[off] = v;
            } else {
                outb[off] = f2bf(v);
            }
        }
    }
}

// Naive attention: one wave per (b, h, q-row); online softmax; shuffle dots.
// ctx MAY EQUAL Qg (per-wave read-before-write on identical location set).
__global__ __launch_bounds__(256) void k_attn(const ushort* Qg,
                                              const ushort* Kg,
                                              const ushort* Vg,
                                              ushort* ctx) {
    int task = blockIdx.x * 4 + (threadIdx.x >> 6);
    int lane = threadIdx.x & 63;
    int b = task >> 13;
    int hh = (task >> 10) & 7;
    int qrow = task & 1023;
    const size_t base = (size_t)(b * 1024) * 512 + hh * 64 + lane;
    float q = bf2f(Qg[base + (size_t)qrow * 512]);
    float mx = -1e30f, l = 0.f, o = 0.f;
    for (int k = 0; k < 1024; k++) {
        float kv = bf2f(Kg[base + (size_t)k * 512]);
        float p = q * kv;
#pragma unroll
        for (int off = 32; off; off >>= 1) p += __shfl_xor(p, off, 64);
        p *= 0.125f;                       // 1/sqrt(64)
        float nm = fmaxf(mx, p);
        float al = __expf(mx - nm);
        float w = __expf(p - nm);
        l = l * al + w;
        o = o * al + w * bf2f(Vg[base + (size_t)k * 512]);
        mx = nm;
    }
    ctx[base + (size_t)qrow * 512] = f2bf(o / l);
}

// LayerNorm over 512; optional bf16 residual; bf16 out. resb MAY EQUAL outb.
__global__ __launch_bounds__(256) void k_ln(const float* x,
                                            const ushort* resb,
                                            const ushort* __restrict__ g,
                                            const ushort* __restrict__ bb,
                                            ushort* outb,
                                            int useRes) {
    int row = blockIdx.x * 4 + (threadIdx.x >> 6);
    int lane = threadIdx.x & 63;
    const float* xr = x + (size_t)row * 512;
    const ushort* rr = resb + (size_t)row * 512;
    float v[8];
    float s = 0.f, sq = 0.f;
#pragma unroll
    for (int j = 0; j < 8; j++) {
        float t = xr[lane + 64 * j];
        if (useRes) t += bf2f(rr[lane + 64 * j]);
        v[j] = t; s += t;
    }
#pragma unroll
    for (int j = 0; j < 8; j++) sq += v[j] * v[j];
#pragma unroll
    for (int off = 32; off; off >>= 1) { s += __shfl_xor(s, off, 64); sq += __shfl_xor(sq, off, 64); }
    float mu = s * (1.f / 512.f);
    float var = sq * (1.f / 512.f) - mu * mu;
    float rstd = rsqrtf(var + 1e-5f);
#pragma unroll
    for (int j = 0; j < 8; j++) {
        int c = lane + 64 * j;
        float y = (v[j] - mu) * rstd * bf2f(g[c]) + bf2f(bb[c]);
        outb[(size_t)row * 512 + c] = f2bf(y);
    }
}

// a_pre[row] = dot(act_bf16[row], e_x)
__global__ __launch_bounds__(256) void k_apre(const ushort* __restrict__ x,
                                              const ushort* __restrict__ ex,
                                              float* __restrict__ out) {
    int row = blockIdx.x * 4 + (threadIdx.x >> 6);
    int lane = threadIdx.x & 63;
    float s = 0.f;
#pragma unroll
    for (int j = 0; j < 8; j++) s += bf2f(x[(size_t)row * 512 + lane + 64 * j]) * bf2f(ex[lane + 64 * j]);
#pragma unroll
    for (int off = 32; off; off >>= 1) s += __shfl_xor(s, off, 64);
    if (lane == 0) out[row] = s;
}

DEVINL float tanh_fast(float x) {
    float e = __expf(-2.f * fabsf(x));
    float th = (1.f - e) / (1.f + e);
    return copysignf(th, x);
}

// Naive LMU scan: ONE block per batch (grid=8, 256 threads). f32 weights.
// cg and ys MAY ALIAS (same element read-then-written by same thread).
__global__ __launch_bounds__(256) void k_scan_naive(
    const float* __restrict__ Whp,    // [512][512] f32
    const float* __restrict__ Wmp,    // [512][256] f32
    const float* __restrict__ Ac,     // [256][256] f32
    const float* __restrict__ Bd,     // [256] f32
    const float* __restrict__ ehp,    // [512] f32
    const float* __restrict__ emp,    // [256] f32
    const float* cg,                  // [8][1024][512] Wx@x
    const float* __restrict__ apre,   // [8][1024]
    float* ys,                        // [8][1024][512] (may == cg)
    void* outbase,                    // d_out
    int hsL, int msL,                 // element bases for this layer
    const uint* dual)
{
    const int b = blockIdx.x, tid = threadIdx.x;
    __shared__ float h_s[512], m_s[256], mn_s[256], red[4], ehs[512], ems[256];
    const uint fl = *dual;
    ehs[tid] = ehp[tid];
    ehs[tid + 256] = ehp[tid + 256];
    ems[tid] = emp[tid];
    h_s[tid] = 0.f; h_s[tid + 256] = 0.f; m_s[tid] = 0.f;
    const float bdv = Bd[tid];
    __syncthreads();

    const float* crow = cg + (size_t)b * 1024 * 512;
    float* ysrow = ys + (size_t)b * 1024 * 512;
    const float* arow = apre + b * 1024;

    for (int t = 0; t < 1024; ++t) {
        // u = x_t.e_x + h.e_h + m.e_m
        float part = h_s[tid] * ehs[tid] + h_s[tid + 256] * ehs[tid + 256]
                   + m_s[tid] * ems[tid];
#pragma unroll
        for (int off = 32; off; off >>= 1) part += __shfl_xor(part, off, 64);
        if ((tid & 63) == 0) red[tid >> 6] = part;
        __syncthreads();
        float u = arow[t] + ((red[0] + red[1]) + (red[2] + red[3]));

        // m_new[tid] = A[tid,:].m + u*B[tid]
        float macc = u * bdv;
        {
            const float* ar = Ac + (size_t)tid * 256;
#pragma unroll 8
            for (int k = 0; k < 256; k += 4) {
                float4 av = *(const float4*)(ar + k);
                macc += av.x * m_s[k] + av.y * m_s[k + 1] + av.z * m_s[k + 2] + av.w * m_s[k + 3];
            }
        }
        mn_s[tid] = macc;
        __syncthreads();

        // h rows tid, tid+256: tanh(cpre + Wh[r].h + Wm[r].m_new)
        float hv[2];
#pragma unroll
        for (int rr = 0; rr < 2; rr++) {
            int r = tid + rr * 256;
            float hacc = crow[(size_t)t * 512 + r];
            const float* wr = Whp + (size_t)r * 512;
#pragma unroll 8
            for (int k4 = 0; k4 < 128; k4++) {
                float4 w = *(const float4*)(wr + k4 * 4);
                const float* hp = &h_s[k4 * 4];
                hacc += w.x * hp[0] + w.y * hp[1] + w.z * hp[2] + w.w * hp[3];
            }
            const float* wm = Wmp + (size_t)r * 256;
#pragma unroll 8
            for (int k4 = 0; k4 < 64; k4++) {
                float4 w = *(const float4*)(wm + k4 * 4);
                const float* mp = &mn_s[k4 * 4];
                hacc += w.x * mp[0] + w.y * mp[1] + w.z * mp[2] + w.w * mp[3];
            }
            hv[rr] = tanh_fast(hacc);
            ysrow[(size_t)t * 512 + r] = hv[rr];
        }
        __syncthreads();
        h_s[tid] = hv[0]; h_s[tid + 256] = hv[1]; m_s[tid] = mn_s[tid];
        __syncthreads();
        if (t == 1023) {
            if (fl) {
                float* ob = (float*)outbase;
                ob[hsL + b * 512 + tid] = hv[0];
                ob[hsL + b * 512 + tid + 256] = hv[1];
                ob[msL + b * 256 + tid] = mn_s[tid];
            } else {
                ushort* ob = (ushort*)outbase;
                ob[hsL + b * 512 + tid] = f2bf(hv[0]);
                ob[hsL + b * 512 + tid + 256] = f2bf(hv[1]);
                ob[msL + b * 256 + tid] = f2bf(mn_s[tid]);
            }
        }
    }
}

// ---------------- launch ---------------------------------------------------
extern "C" void kernel_launch(void* const* d_in, const int* in_sizes, int n_in,
                              void* d_out, int out_size, void* d_ws, size_t ws_size,
                              hipStream_t stream) {
    char* ws = (char*)d_ws;
    uint* flag = (uint*)(ws + OFF_FLAG);
    float* A_c = (float*)(ws + OFF_A);
    float* B_c = (float*)(ws + OFF_BD);
    float* apre = (float*)(ws + OFF_APRE);
    ushort* actb = (ushort*)(ws + OFF_ACTB);
    ushort* qb_ = (ushort*)(ws + OFF_Q);
    ushort* kb_ = (ushort*)(ws + OFF_KV);
    ushort* vb_ = (ushort*)(ws + OFF_KV + 8388608u);
    ushort* ctx = qb_;
    float* eo = (float*)(ws + OFF_KV);
    float* cbuf = eo;
    float* ysb = cbuf;
    double* Mm = (double*)(ws + OFF_KV);            // expm lives in KV pre-pipeline
    double* Tt = (double*)(ws + OFF_KV + 528640u);
    double* Pp = (double*)(ws + OFF_KV + 1057280u);

    // 1) dtype sniff
    k_sniff<<<1, 64, 0, stream>>>((const ushort*)d_in[0], flag);

    // 2) canonicalize inputs. f32 targets: e_h(14), e_m(15), Wh(17), Wm(18).
    static const int isF32[23] = {0,0,0, 0,0,0,0,0,0,0,0, 0,0, 0,1,1, 0,1,1, 0,0,0,0};
    const void* cp[23]; // canonical pointers
    {
        size_t o16 = 0, o32 = 0;
        for (int i = 0; i < 23; i++) {
            int n = in_sizes[i];
            if (isF32[i]) {
                float* dst = (float*)(ws + OFF_B32 + o32 * 4);
                k_cvt32<<<(n + 255) / 256, 256, 0, stream>>>(d_in[i], dst, n, flag);
                cp[i] = dst;
                o32 += (size_t)((n + 127) & ~127);
            } else {
                ushort* dst = (ushort*)(ws + OFF_B16 + o16 * 2);
                k_cvt16<<<(n + 255) / 256, 256, 0, stream>>>(d_in[i], dst, n, flag);
                cp[i] = dst;
                o16 += (size_t)((n + 127) & ~127);
            }
        }
    }
    const ushort* xb    = (const ushort*)cp[0];
    const ushort* W_in  = (const ushort*)cp[1];
    const ushort* b_in  = (const ushort*)cp[2];
    const ushort* Wq    = (const ushort*)cp[3];
    const ushort* bq    = (const ushort*)cp[4];
    const ushort* Wk    = (const ushort*)cp[5];
    const ushort* bk    = (const ushort*)cp[6];
    const ushort* Wv    = (const ushort*)cp[7];
    const ushort* bv    = (const ushort*)cp[8];
    const ushort* Wo    = (const ushort*)cp[9];
    const ushort* bo    = (const ushort*)cp[10];
    const ushort* g_at  = (const ushort*)cp[11];
    const ushort* b_at  = (const ushort*)cp[12];
    const ushort* e_x   = (const ushort*)cp[13];
    const float*  e_h   = (const float*)cp[14];
    const float*  e_m   = (const float*)cp[15];
    const ushort* Wx    = (const ushort*)cp[16];
    const float*  Wh    = (const float*)cp[17];
    const float*  Wm    = (const float*)cp[18];
    const ushort* g_lnp = (const ushort*)cp[19];
    const ushort* b_lnp = (const ushort*)cp[20];
    const ushort* W_out = (const ushort*)cp[21];
    const ushort* b_out = (const ushort*)cp[22];

    // 3) device expm(LegS) in f64 (KV region; done before KV is reused)
    k_expm_init<<<259, 256, 0, stream>>>(Mm, Tt);
    double* cur = Tt; double* oth = Pp;
    for (int k = 20; k >= 1; k--) {
        k_expm_mul<<<259, 256, 0, stream>>>(Mm, cur, oth, k);
        std::swap(cur, oth);
    }
    for (int r = 0; r < 11; r++) {
        k_expm_mul<<<259, 256, 0, stream>>>(Mm, cur, oth, 0);
        std::swap(cur, oth);
    }
    k_expm_extract<<<256, 256, 0, stream>>>(cur, A_c, B_c);

    // 4) network
    k_in_proj<<<16384, 256, 0, stream>>>(xb, W_in, b_in, actb);

    dim3 gg(8, 128);
    for (int L = 0; L < NLAYER; L++) {
        const size_t wofs = (size_t)L * 512 * 512;
        k_gemm<<<gg, 256, 0, stream>>>(actb, Wq + wofs, bq + L * 512, nullptr, qb_, 8192, 512, 512, nullptr);
        k_gemm<<<gg, 256, 0, stream>>>(actb, Wk + wofs, bk + L * 512, nullptr, kb_, 8192, 512, 512, nullptr);
        k_gemm<<<gg, 256, 0, stream>>>(actb, Wv + wofs, bv + L * 512, nullptr, vb_, 8192, 512, 512, nullptr);
        k_attn<<<16384, 256, 0, stream>>>(qb_, kb_, vb_, ctx);
        k_gemm<<<gg, 256, 0, stream>>>(ctx, Wo + wofs, bo + L * 512, eo, nullptr, 8192, 512, 512, nullptr);
        k_ln<<<2048, 256, 0, stream>>>(eo, actb, g_at + L * 512, b_at + L * 512, actb, 1);
        k_apre<<<2048, 256, 0, stream>>>(actb, e_x + L * 512, apre);
        k_gemm<<<gg, 256, 0, stream>>>(actb, Wx + wofs, nullptr, cbuf, nullptr, 8192, 512, 512, nullptr);
        k_scan_naive<<<8, 256, 0, stream>>>(Wh + wofs, Wm + (size_t)L * 512 * 256,
                                            A_c, B_c, e_h + L * 512, e_m + L * 256,
                                            cbuf, apre, ysb,
                                            d_out, HS_OFF + L * 4096, MS_OFF + L * 2048,
                                            flag);
        k_ln<<<2048, 256, 0, stream>>>(ysb, actb, g_lnp + L * 512, b_lnp + L * 512, actb, 0);
    }
    k_gemm<<<gg, 256, 0, stream>>>(actb, W_out, b_out, (float*)d_out, (ushort*)d_out, 8192, 512, 512, flag);
}

// Round 7
// 46091.882 us; speedup vs baseline: 4.7896x; 4.7896x over previous
//
#include <hip/hip_runtime.h>
#include <utility>

// ---------------------------------------------------------------------------
// LMUEncoder on MI355X — fast scan round.
// Inputs are f32 (verified round 6); canonicalized into ws (bf16 for GEMM
// weights/acts, f32 for scan weights) via device-side dtype sniff.
// Scan: 64 WGs (8 per batch), Wh/WmA in VGPRs, A-slice in LDS, cross-WG
// state exchange via LLC with monotonic release/acquire flags.
// B=8, T=1024, D_IN=80, H=512, MEM=256, L=4, NH=8, dk=64.
// ---------------------------------------------------------------------------

typedef unsigned int uint;
typedef unsigned short ushort;
typedef __attribute__((ext_vector_type(8))) short short8;
typedef __attribute__((ext_vector_type(4))) float f32x4;

#define DEVINL static __device__ __forceinline__

DEVINL float bf2f(ushort u) { uint x = ((uint)u) << 16; float f; __builtin_memcpy(&f, &x, 4); return f; }
DEVINL ushort f2bf(float f) {
    uint u; __builtin_memcpy(&u, &f, 4);
    uint r = (u + 0x7fffu + ((u >> 16) & 1u)) >> 16;
    return (ushort)r;
}

DEVINL float atomLoad(const float* p) {
    return __hip_atomic_load(p, __ATOMIC_RELAXED, __HIP_MEMORY_SCOPE_AGENT);
}
DEVINL void atomStore(float* p, float v) {
    __hip_atomic_store(p, v, __ATOMIC_RELAXED, __HIP_MEMORY_SCOPE_AGENT);
}

// ---------------- sizes / ws layout (bytes, 256-aligned) -------------------
#define DIN 80
#define NLAYER 4
#define ENC_SZ (8*1024*512)
#define HS_OFF ENC_SZ
#define MS_OFF (ENC_SZ + 4*8*512)
#define NEXP 257

#define OFF_B16    0u           // bf16 blob (~12.45 MB used)
#define OFF_B32    13107200u    // f32 blob (~6.3 MB used)
#define OFF_FLAG   19922944u    // dtype flag (1 uint) + scan flags (64 uint)
#define OFF_SFLAGS 19923200u    // 64 uint scan flags
#define OFF_A      19923968u    // 256*256 f32
#define OFF_BD     20972544u    // 256 f32
#define OFF_APRE   20973568u    // 8*1024 f32
#define OFF_ACTB   21006336u    // 8192*512 bf16 = 8388608
#define OFF_Q      29394944u    // 8192*512 bf16 (ctx aliases Q)
#define OFF_KV     37783552u    // K|V bf16 16MB; expm f64 + eo/cbuf/ys f32 alias
#define OFF_WMA    54560768u    // 512*260 f32 = 532480 (col 256 = WmB)
#define OFF_S12    55093504u    // 2*8*16 f32
#define OFF_HB     55094528u    // 2*8*512 f32
#define OFF_MB     55127296u    // 2*8*256 f32
// total = 55143680 bytes ~ 52.6 MB

// ---------------- dtype sniffer --------------------------------------------
__global__ __launch_bounds__(64) void k_sniff(const ushort* x, uint* flag) {
    int i = threadIdx.x;
    ushort u = x[2 * i];
    uint e = (u >> 7) & 0xffu;
    bool ok = (u == 0) || (e >= 100u && e <= 140u);
    unsigned long long m = __ballot(ok);
    if (i == 0) *flag = (m == ~0ull) ? 0u : 1u;   // 0 = bf16 inputs, 1 = f32
}

__global__ __launch_bounds__(256) void k_cvt16(const void* src, ushort* dst, int n,
                                               const uint* flag) {
    int i = blockIdx.x * 256 + threadIdx.x;
    if (i >= n) return;
    dst[i] = (*flag) ? f2bf(((const float*)src)[i]) : ((const ushort*)src)[i];
}
__global__ __launch_bounds__(256) void k_cvt32(const void* src, float* dst, int n,
                                               const uint* flag) {
    int i = blockIdx.x * 256 + threadIdx.x;
    if (i >= n) return;
    dst[i] = (*flag) ? ((const float*)src)[i] : bf2f(((const ushort*)src)[i]);
}

// ---------------- device expm (LegS, f64) ----------------------------------
// ||M||_1 = 512 -> scale 2^-11 (norm 0.25), Taylor-20 Horner, square x11.
// Also zeroes the 64 scan flags.
__global__ __launch_bounds__(256) void k_expm_init(double* M, double* T, uint* sflags) {
    int idx = blockIdx.x * 256 + threadIdx.x;
    if (idx < 64) sflags[idx] = 0u;
    if (idx >= NEXP * NEXP) return;
    int i = idx / NEXP, j = idx - i * NEXP;
    double v = 0.0;
    if (i < 256) {
        double R = (2.0 * i + 1.0) / 128.0;
        if (j < 256) v = ((i < j) ? -1.0 : (((i - j) & 1) ? 1.0 : -1.0)) * R;
        else         v = ((i & 1) ? -1.0 : 1.0) * R;
    }
    M[idx] = v * (1.0 / 2048.0);
    T[idx] = (i == j) ? 1.0 : 0.0;
}

__global__ __launch_bounds__(256) void k_expm_mul(const double* M, const double* src,
                                                  double* dst, int k) {
    int idx = blockIdx.x * 256 + threadIdx.x;
    if (idx >= NEXP * NEXP) return;
    int i = idx / NEXP, j = idx - i * NEXP;
    const double* a = (k ? M : src) + (size_t)i * NEXP;
    double acc = 0.0;
    for (int l = 0; l < NEXP; l++) acc += a[l] * src[(size_t)l * NEXP + j];
    dst[idx] = k ? (acc / (double)k + ((i == j) ? 1.0 : 0.0)) : acc;
}

__global__ __launch_bounds__(256) void k_expm_extract(const double* P, float* A, float* B) {
    int idx = blockIdx.x * 256 + threadIdx.x;
    if (idx >= 256 * 256) return;
    int i = idx >> 8, j = idx & 255;
    A[idx] = (float)P[(size_t)i * NEXP + j];
    if (j == 0) B[i] = (float)P[(size_t)i * NEXP + 256];
}

// ---------------- network kernels ------------------------------------------

__global__ __launch_bounds__(256) void k_in_proj(const ushort* __restrict__ x,
                                                 const ushort* __restrict__ W,
                                                 const ushort* __restrict__ bias,
                                                 ushort* __restrict__ outb) {
    int gid = blockIdx.x * 256 + threadIdx.x;
    int n = gid & 511;
    int row = gid >> 9;
    const ushort* xr = x + row * DIN;
    const ushort* wr = W + n * DIN;
    float acc = bf2f(bias[n]);
#pragma unroll
    for (int k = 0; k < DIN; k++) acc += bf2f(xr[k]) * bf2f(wr[k]);
    outb[gid] = f2bf(acc);
}

// C[M][N] = A[M][K] @ W[N][K]^T (+bias). dual!=null: write as f32 if *dual
// else bf16 (same buffer). dual==null: plain outf/outb writes.
__global__ __launch_bounds__(256) void k_gemm(const ushort* A,
                                              const ushort* W,
                                              const ushort* bias,
                                              float* outf,
                                              ushort* outb,
                                              int M, int N, int K,
                                              const uint* dual) {
    int tn = blockIdx.x * 64;
    int tm = blockIdx.y * 64;
    int wave = threadIdx.x >> 6;
    int lane = threadIdx.x & 63;
    int l16 = lane & 15, q = lane >> 4;
    uint fl = dual ? *dual : 2u;
    const ushort* arow = A + (size_t)(tm + wave * 16 + l16) * K + q * 8;
    const ushort* w0 = W + (size_t)(tn + 0 + l16) * K + q * 8;
    const ushort* w1 = W + (size_t)(tn + 16 + l16) * K + q * 8;
    const ushort* w2 = W + (size_t)(tn + 32 + l16) * K + q * 8;
    const ushort* w3 = W + (size_t)(tn + 48 + l16) * K + q * 8;
    f32x4 acc[4];
#pragma unroll
    for (int j = 0; j < 4; j++) acc[j] = (f32x4){0.f, 0.f, 0.f, 0.f};
    for (int kk = 0; kk < K; kk += 32) {
        short8 a = *(const short8*)(arow + kk);
        short8 b0 = *(const short8*)(w0 + kk);
        short8 b1 = *(const short8*)(w1 + kk);
        short8 b2 = *(const short8*)(w2 + kk);
        short8 b3 = *(const short8*)(w3 + kk);
        acc[0] = __builtin_amdgcn_mfma_f32_16x16x32_bf16(a, b0, acc[0], 0, 0, 0);
        acc[1] = __builtin_amdgcn_mfma_f32_16x16x32_bf16(a, b1, acc[1], 0, 0, 0);
        acc[2] = __builtin_amdgcn_mfma_f32_16x16x32_bf16(a, b2, acc[2], 0, 0, 0);
        acc[3] = __builtin_amdgcn_mfma_f32_16x16x32_bf16(a, b3, acc[3], 0, 0, 0);
    }
#pragma unroll
    for (int j = 0; j < 4; j++) {
        int col = tn + j * 16 + l16;
        float bv = bias ? bf2f(bias[col]) : 0.f;
#pragma unroll
        for (int i = 0; i < 4; i++) {
            int m = tm + wave * 16 + q * 4 + i;
            float v = acc[j][i] + bv;
            size_t off = (size_t)m * N + col;
            if (fl == 2u) {
                if (outf) outf[off] = v;
                if (outb) outb[off] = f2bf(v);
            } else if (fl == 1u) {
                outf[off] = v;
            } else {
                outb[off] = f2bf(v);
            }
        }
    }
}

// Naive attention: one wave per (b, h, q-row); online softmax; shuffle dots.
__global__ __launch_bounds__(256) void k_attn(const ushort* Qg,
                                              const ushort* Kg,
                                              const ushort* Vg,
                                              ushort* ctx) {
    int task = blockIdx.x * 4 + (threadIdx.x >> 6);
    int lane = threadIdx.x & 63;
    int b = task >> 13;
    int hh = (task >> 10) & 7;
    int qrow = task & 1023;
    const size_t base = (size_t)(b * 1024) * 512 + hh * 64 + lane;
    float q = bf2f(Qg[base + (size_t)qrow * 512]);
    float mx = -1e30f, l = 0.f, o = 0.f;
    for (int k = 0; k < 1024; k++) {
        float kv = bf2f(Kg[base + (size_t)k * 512]);
        float p = q * kv;
#pragma unroll
        for (int off = 32; off; off >>= 1) p += __shfl_xor(p, off, 64);
        p *= 0.125f;
        float nm = fmaxf(mx, p);
        float al = __expf(mx - nm);
        float w = __expf(p - nm);
        l = l * al + w;
        o = o * al + w * bf2f(Vg[base + (size_t)k * 512]);
        mx = nm;
    }
    ctx[base + (size_t)qrow * 512] = f2bf(o / l);
}

// LayerNorm over 512; optional bf16 residual; bf16 out. resb MAY EQUAL outb.
__global__ __launch_bounds__(256) void k_ln(const float* x,
                                            const ushort* resb,
                                            const ushort* __restrict__ g,
                                            const ushort* __restrict__ bb,
                                            ushort* outb,
                                            int useRes) {
    int row = blockIdx.x * 4 + (threadIdx.x >> 6);
    int lane = threadIdx.x & 63;
    const float* xr = x + (size_t)row * 512;
    const ushort* rr = resb + (size_t)row * 512;
    float v[8];
    float s = 0.f, sq = 0.f;
#pragma unroll
    for (int j = 0; j < 8; j++) {
        float t = xr[lane + 64 * j];
        if (useRes) t += bf2f(rr[lane + 64 * j]);
        v[j] = t; s += t;
    }
#pragma unroll
    for (int j = 0; j < 8; j++) sq += v[j] * v[j];
#pragma unroll
    for (int off = 32; off; off >>= 1) { s += __shfl_xor(s, off, 64); sq += __shfl_xor(sq, off, 64); }
    float mu = s * (1.f / 512.f);
    float var = sq * (1.f / 512.f) - mu * mu;
    float rstd = rsqrtf(var + 1e-5f);
#pragma unroll
    for (int j = 0; j < 8; j++) {
        int c = lane + 64 * j;
        float y = (v[j] - mu) * rstd * bf2f(g[c]) + bf2f(bb[c]);
        outb[(size_t)row * 512 + c] = f2bf(y);
    }
}

// a_pre[row] = dot(act_bf16[row], e_x_bf16)
__global__ __launch_bounds__(256) void k_apre(const ushort* __restrict__ x,
                                              const ushort* __restrict__ ex,
                                              float* __restrict__ out) {
    int row = blockIdx.x * 4 + (threadIdx.x >> 6);
    int lane = threadIdx.x & 63;
    float s = 0.f;
#pragma unroll
    for (int j = 0; j < 8; j++) s += bf2f(x[(size_t)row * 512 + lane + 64 * j]) * bf2f(ex[lane + 64 * j]);
#pragma unroll
    for (int off = 32; off; off >>= 1) s += __shfl_xor(s, off, 64);
    if (lane == 0) out[row] = s;
}

// WmA[j][k] = sum_l Wm[j][l]*A[l][k] (k<256); col 256 = Wm@B. stride 260. f32.
__global__ __launch_bounds__(256) void k_wma(const float* __restrict__ Wm,
                                             const float* __restrict__ A,
                                             const float* __restrict__ Bd,
                                             float* __restrict__ out) {
    int j = blockIdx.x;
    int k = blockIdx.y * 256 + threadIdx.x;
    if (k >= 257) return;
    float acc = 0.f;
    for (int l = 0; l < 256; l++) {
        float w = Wm[j * 256 + l];
        float av = (k < 256) ? A[l * 256 + k] : Bd[l];
        acc += w * av;
    }
    out[j * 260 + k] = acc;
}

DEVINL float tanh_fast(float x) {
    float e = __expf(-2.f * fabsf(x));
    float th = (1.f - e) / (1.f + e);
    return copysignf(th, x);
}

// Fast LMU scan: 64 blocks (8 per batch), 256 threads. Weights in VGPRs.
// Flags monotonic: layer*1024+t. cg and ys MAY ALIAS (in-place).
__global__ __launch_bounds__(256, 2) void k_scan(
    const float* __restrict__ Whp,    // [512][512] f32 (layer slice)
    const float* __restrict__ WmA,    // [512][260] f32, col256 = WmB
    const float* __restrict__ Ac,     // [256][256] f32
    const float* __restrict__ Bd,     // [256] f32
    const float* __restrict__ ehp,    // [512] f32
    const float* __restrict__ emp,    // [256] f32
    const float* cg,                  // [8][1024][512] Wx@x
    const float* __restrict__ apre,   // [8][1024]
    float* ys,                        // [8][1024][512] (may == cg)
    float* Hbuf,                      // [2][8][512]
    float* Mbuf,                      // [2][8][256]
    float* S12,                       // [2][8][16]
    uint* flags,                      // [8][8]
    void* outbase,                    // d_out
    int hsL, int msL,                 // element bases for this layer
    int layer,
    const uint* dual) {
    const int tid = threadIdx.x;
    const int b = blockIdx.x >> 3, g = blockIdx.x & 7;
    const int r = tid & 63, s = tid >> 6;
    const int rz = tid & 31, sz = tid >> 5;
    __shared__ float h_s[512], m_s[256], red[256], red2[256], up[16], ehs[64], ems[32];
    __shared__ float A_lds[32 * 260];
    const uint fl = *dual;

    // ---- preamble: weights into VGPRs / LDS ----
    float wh[128];   // Wh row (g*64+r), cols s*128 .. +127
    {
        const float* pw = Whp + (size_t)(g * 64 + r) * 512 + s * 128;
#pragma unroll
        for (int i = 0; i < 32; i++) {
            float4 v = *(const float4*)(pw + i * 4);
            wh[i * 4 + 0] = v.x; wh[i * 4 + 1] = v.y; wh[i * 4 + 2] = v.z; wh[i * 4 + 3] = v.w;
        }
    }
    float wma[64];   // WmA row (g*64+r), cols s*64 .. +63
    {
        const float* p = WmA + (size_t)(g * 64 + r) * 260 + s * 64;
#pragma unroll
        for (int i = 0; i < 16; i++) {
            float4 v = *(const float4*)(p + i * 4);
            wma[i * 4 + 0] = v.x; wma[i * 4 + 1] = v.y; wma[i * 4 + 2] = v.z; wma[i * 4 + 3] = v.w;
        }
    }
    float wmb = WmA[(size_t)(g * 64 + r) * 260 + 256];
    float bdv = Bd[g * 32 + rz];
#pragma unroll
    for (int i = 0; i < 8; i++) {
        int idx4 = i * 256 + tid;      // 2048 float4s
        int row = idx4 >> 6;
        int c4 = (idx4 & 63) * 4;
        *(float4*)&A_lds[row * 260 + c4] = *(const float4*)&Ac[(size_t)(g * 32 + row) * 256 + c4];
    }
    if (tid < 64) ehs[tid] = ehp[g * 64 + tid];
    if (tid >= 64 && tid < 96) ems[tid - 64] = emp[g * 32 + (tid - 64)];
    __syncthreads();

    uint* myflags = flags + b * 8;
    const float* crow = cg + (size_t)(b * 1024) * 512 + g * 64;
    const float* arow = apre + b * 1024;
    float* ysrow = ys + (size_t)(b * 1024) * 512 + g * 64;

    for (int t = 1; t <= 1024; ++t) {
        const int pp = (t - 1) & 1, cp = t & 1;
        float cpre = (tid < 64) ? crow[(size_t)(t - 1) * 512 + tid] : 0.f;  // prefetch under wait
        float av = arow[t - 1];
        if (t == 1) {
            float4 zz = {0.f, 0.f, 0.f, 0.f};
            if (tid < 128) *(float4*)&h_s[tid * 4] = zz;
            else if (tid < 192) *(float4*)&m_s[(tid - 128) * 4] = zz;
            if (tid < 16) up[tid] = 0.f;
            __syncthreads();
        } else {
            const uint target = (uint)(layer * 1024 + t - 1);
            if (tid < 8) {
                int guard = 0;
                while (__hip_atomic_load(&myflags[tid], __ATOMIC_RELAXED, __HIP_MEMORY_SCOPE_AGENT) < target
                       && ++guard < (1 << 27)) {}
            }
            __syncthreads();
            __builtin_amdgcn_fence(__ATOMIC_ACQUIRE, "agent");
            if (tid < 128) {
#pragma unroll
                for (int k = 0; k < 4; k++)
                    h_s[tid * 4 + k] = atomLoad(&Hbuf[(pp * 8 + b) * 512 + tid * 4 + k]);
            } else if (tid < 192) {
                int i = tid - 128;
#pragma unroll
                for (int k = 0; k < 4; k++)
                    m_s[i * 4 + k] = atomLoad(&Mbuf[(pp * 8 + b) * 256 + i * 4 + k]);
            } else if (tid < 208) {
                up[tid - 192] = atomLoad(&S12[(pp * 8 + b) * 16 + (tid - 192)]);
            }
            __syncthreads();
        }
        float u = av;
#pragma unroll
        for (int i = 0; i < 16; i++) u += up[i];

        // h-partial: row g*64+r, k-split s
        float a0 = 0.f, a1 = 0.f, a2 = 0.f, a3 = 0.f;
        {
            const float* hp = &h_s[s * 128];
#pragma unroll
            for (int k4 = 0; k4 < 32; k4++) {
                float4 hv = *(const float4*)&hp[k4 * 4];
                a0 += wh[k4 * 4 + 0] * hv.x; a1 += wh[k4 * 4 + 1] * hv.y;
                a2 += wh[k4 * 4 + 2] * hv.z; a3 += wh[k4 * 4 + 3] * hv.w;
            }
            const float* mp = &m_s[s * 64];
#pragma unroll
            for (int k4 = 0; k4 < 16; k4++) {
                float4 mv = *(const float4*)&mp[k4 * 4];
                a0 += wma[k4 * 4 + 0] * mv.x; a1 += wma[k4 * 4 + 1] * mv.y;
                a2 += wma[k4 * 4 + 2] * mv.z; a3 += wma[k4 * 4 + 3] * mv.w;
            }
        }
        float qa = (a0 + a1) + (a2 + a3);
        // m-partial: row g*32+rz, k-split sz
        float z0 = 0.f, z1 = 0.f, z2 = 0.f, z3 = 0.f;
        {
            const float* ap = &A_lds[rz * 260 + sz * 32];
            const float* mp = &m_s[sz * 32];
#pragma unroll
            for (int k4 = 0; k4 < 8; k4++) {
                float4 avv = *(const float4*)&ap[k4 * 4];
                float4 mvv = *(const float4*)&mp[k4 * 4];
                z0 += avv.x * mvv.x; z1 += avv.y * mvv.y; z2 += avv.z * mvv.z; z3 += avv.w * mvv.w;
            }
        }
        float za = (z0 + z1) + (z2 + z3);
        red[r * 4 + s] = qa;
        red2[rz * 8 + sz] = za;
        __syncthreads();

        float hn = 0.f, mn = 0.f;
        if (tid < 64) {
            float4 rv = *(const float4*)&red[tid * 4];
            float pre = cpre + u * wmb + (rv.x + rv.y) + (rv.z + rv.w);
            hn = tanh_fast(pre);
            atomStore(&Hbuf[(cp * 8 + b) * 512 + g * 64 + tid], hn);
            ysrow[(size_t)(t - 1) * 512 + tid] = hn;
            float pe = ehs[tid] * hn;
#pragma unroll
            for (int off = 32; off; off >>= 1) pe += __shfl_xor(pe, off, 64);
            if (tid == 0) atomStore(&S12[(cp * 8 + b) * 16 + g], pe);
        } else if (tid < 96) {
            int i = tid - 64;
            float4 r0 = *(const float4*)&red2[i * 8];
            float4 r1 = *(const float4*)&red2[i * 8 + 4];
            mn = ((r0.x + r0.y) + (r0.z + r0.w)) + ((r1.x + r1.y) + (r1.z + r1.w)) + u * bdv;
            atomStore(&Mbuf[(cp * 8 + b) * 256 + g * 32 + i], mn);
            float pe = ems[i] * mn;
#pragma unroll
            for (int off = 16; off; off >>= 1) pe += __shfl_xor(pe, off, 64);
            if (i == 0) atomStore(&S12[(cp * 8 + b) * 16 + 8 + g], pe);
        }
        if (t == 1024) {
            if (fl) {
                float* ob = (float*)outbase;
                if (tid < 64) ob[hsL + b * 512 + g * 64 + tid] = hn;
                else if (tid < 96) ob[msL + b * 256 + g * 32 + (tid - 64)] = mn;
            } else {
                ushort* ob = (ushort*)outbase;
                if (tid < 64) ob[hsL + b * 512 + g * 64 + tid] = f2bf(hn);
                else if (tid < 96) ob[msL + b * 256 + g * 32 + (tid - 64)] = f2bf(mn);
            }
        }
        __syncthreads();
        if (tid == 0)
            __hip_atomic_store(&myflags[g], (uint)(layer * 1024 + t), __ATOMIC_RELEASE, __HIP_MEMORY_SCOPE_AGENT);
    }
}

// ---------------- launch ---------------------------------------------------
extern "C" void kernel_launch(void* const* d_in, const int* in_sizes, int n_in,
                              void* d_out, int out_size, void* d_ws, size_t ws_size,
                              hipStream_t stream) {
    char* ws = (char*)d_ws;
    uint* flag = (uint*)(ws + OFF_FLAG);
    uint* sflags = (uint*)(ws + OFF_SFLAGS);
    float* A_c = (float*)(ws + OFF_A);
    float* B_c = (float*)(ws + OFF_BD);
    float* apre = (float*)(ws + OFF_APRE);
    float* WmAb = (float*)(ws + OFF_WMA);
    float* S12f = (float*)(ws + OFF_S12);
    float* Hb = (float*)(ws + OFF_HB);
    float* Mb = (float*)(ws + OFF_MB);
    ushort* actb = (ushort*)(ws + OFF_ACTB);
    ushort* qb_ = (ushort*)(ws + OFF_Q);
    ushort* kb_ = (ushort*)(ws + OFF_KV);
    ushort* vb_ = (ushort*)(ws + OFF_KV + 8388608u);
    ushort* ctx = qb_;
    float* eo = (float*)(ws + OFF_KV);
    float* cbuf = eo;
    float* ysb = cbuf;
    double* Mm = (double*)(ws + OFF_KV);            // expm lives in KV pre-pipeline
    double* Tt = (double*)(ws + OFF_KV + 528640u);
    double* Pp = (double*)(ws + OFF_KV + 1057280u);

    // 1) dtype sniff
    k_sniff<<<1, 64, 0, stream>>>((const ushort*)d_in[0], flag);

    // 2) canonicalize inputs. f32 targets: e_h(14), e_m(15), Wh(17), Wm(18).
    static const int isF32[23] = {0,0,0, 0,0,0,0,0,0,0,0, 0,0, 0,1,1, 0,1,1, 0,0,0,0};
    const void* cp[23];
    {
        size_t o16 = 0, o32 = 0;
        for (int i = 0; i < 23; i++) {
            int n = in_sizes[i];
            if (isF32[i]) {
                float* dst = (float*)(ws + OFF_B32 + o32 * 4);
                k_cvt32<<<(n + 255) / 256, 256, 0, stream>>>(d_in[i], dst, n, flag);
                cp[i] = dst;
                o32 += (size_t)((n + 127) & ~127);
            } else {
                ushort* dst = (ushort*)(ws + OFF_B16 + o16 * 2);
                k_cvt16<<<(n + 255) / 256, 256, 0, stream>>>(d_in[i], dst, n, flag);
                cp[i] = dst;
                o16 += (size_t)((n + 127) & ~127);
            }
        }
    }
    const ushort* xb    = (const ushort*)cp[0];
    const ushort* W_in  = (const ushort*)cp[1];
    const ushort* b_in  = (const ushort*)cp[2];
    const ushort* Wq    = (const ushort*)cp[3];
    const ushort* bq    = (const ushort*)cp[4];
    const ushort* Wk    = (const ushort*)cp[5];
    const ushort* bk    = (const ushort*)cp[6];
    const ushort* Wv    = (const ushort*)cp[7];
    const ushort* bv    = (const ushort*)cp[8];
    const ushort* Wo    = (const ushort*)cp[9];
    const ushort* bo    = (const ushort*)cp[10];
    const ushort* g_at  = (const ushort*)cp[11];
    const ushort* b_at  = (const ushort*)cp[12];
    const ushort* e_x   = (const ushort*)cp[13];
    const float*  e_h   = (const float*)cp[14];
    const float*  e_m   = (const float*)cp[15];
    const ushort* Wx    = (const ushort*)cp[16];
    const float*  Wh    = (const float*)cp[17];
    const float*  Wm    = (const float*)cp[18];
    const ushort* g_lnp = (const ushort*)cp[19];
    const ushort* b_lnp = (const ushort*)cp[20];
    const ushort* W_out = (const ushort*)cp[21];
    const ushort* b_out = (const ushort*)cp[22];

    // 3) device expm(LegS) in f64 (KV region; done before KV is reused)
    k_expm_init<<<259, 256, 0, stream>>>(Mm, Tt, sflags);
    double* cur = Tt; double* oth = Pp;
    for (int k = 20; k >= 1; k--) {
        k_expm_mul<<<259, 256, 0, stream>>>(Mm, cur, oth, k);
        std::swap(cur, oth);
    }
    for (int r = 0; r < 11; r++) {
        k_expm_mul<<<259, 256, 0, stream>>>(Mm, cur, oth, 0);
        std::swap(cur, oth);
    }
    k_expm_extract<<<256, 256, 0, stream>>>(cur, A_c, B_c);

    // 4) network
    k_in_proj<<<16384, 256, 0, stream>>>(xb, W_in, b_in, actb);

    dim3 gg(8, 128);
    for (int L = 0; L < NLAYER; L++) {
        const size_t wofs = (size_t)L * 512 * 512;
        k_gemm<<<gg, 256, 0, stream>>>(actb, Wq + wofs, bq + L * 512, nullptr, qb_, 8192, 512, 512, nullptr);
        k_gemm<<<gg, 256, 0, stream>>>(actb, Wk + wofs, bk + L * 512, nullptr, kb_, 8192, 512, 512, nullptr);
        k_gemm<<<gg, 256, 0, stream>>>(actb, Wv + wofs, bv + L * 512, nullptr, vb_, 8192, 512, 512, nullptr);
        k_attn<<<16384, 256, 0, stream>>>(qb_, kb_, vb_, ctx);
        k_gemm<<<gg, 256, 0, stream>>>(ctx, Wo + wofs, bo + L * 512, eo, nullptr, 8192, 512, 512, nullptr);
        k_ln<<<2048, 256, 0, stream>>>(eo, actb, g_at + L * 512, b_at + L * 512, actb, 1);
        k_wma<<<dim3(512, 2), 256, 0, stream>>>(Wm + (size_t)L * 512 * 256, A_c, B_c, WmAb);
        k_apre<<<2048, 256, 0, stream>>>(actb, e_x + L * 512, apre);
        k_gemm<<<gg, 256, 0, stream>>>(actb, Wx + wofs, nullptr, cbuf, nullptr, 8192, 512, 512, nullptr);
        k_scan<<<64, 256, 0, stream>>>(Wh + wofs, WmAb, A_c, B_c,
                                       e_h + L * 512, e_m + L * 256,
                                       cbuf, apre, ysb,
                                       Hb, Mb, S12f, sflags,
                                       d_out, HS_OFF + L * 4096, MS_OFF + L * 2048,
                                       L, flag);
        k_ln<<<2048, 256, 0, stream>>>(ysb, actb, g_lnp + L * 512, b_lnp + L * 512, actb, 0);
    }
    k_gemm<<<gg, 256, 0, stream>>>(actb, W_out, b_out, (float*)d_out, (ushort*)d_out, 8192, 512, 512, flag);
}

// Round 8
// 27175.327 us; speedup vs baseline: 8.1235x; 1.6961x over previous
//
#include <hip/hip_runtime.h>
#include <utility>

// ---------------------------------------------------------------------------
// LMUEncoder on MI355X — flash attention + XCD-colocated scan.
// Inputs f32 (dtype-sniffed, canonicalized: bf16 for GEMM/attn, f32 for scan).
// Scan: 64 WGs, b=blockIdx&7 so one batch's 8 WGs share an XCD (blk%8 map);
// weights in VGPRs, state exchange via agent-scope atomics + flags.
// Flash: MFMA QK^T + PV, online softmax, LDS P round-trip (wave*16 fix).
// B=8, T=1024, D_IN=80, H=512, MEM=256, L=4, NH=8, dk=64.
// ---------------------------------------------------------------------------

typedef unsigned int uint;
typedef unsigned short ushort;
typedef __attribute__((ext_vector_type(8))) short short8;
typedef __attribute__((ext_vector_type(4))) float f32x4;

#define DEVINL static __device__ __forceinline__

DEVINL float bf2f(ushort u) { uint x = ((uint)u) << 16; float f; __builtin_memcpy(&f, &x, 4); return f; }
DEVINL ushort f2bf(float f) {
    uint u; __builtin_memcpy(&u, &f, 4);
    uint r = (u + 0x7fffu + ((u >> 16) & 1u)) >> 16;
    return (ushort)r;
}

DEVINL float atomLoad(const float* p) {
    return __hip_atomic_load(p, __ATOMIC_RELAXED, __HIP_MEMORY_SCOPE_AGENT);
}
DEVINL void atomStore(float* p, float v) {
    __hip_atomic_store(p, v, __ATOMIC_RELAXED, __HIP_MEMORY_SCOPE_AGENT);
}

// ---------------- sizes / ws layout (bytes, 256-aligned) -------------------
#define DIN 80
#define NLAYER 4
#define ENC_SZ (8*1024*512)
#define HS_OFF ENC_SZ
#define MS_OFF (ENC_SZ + 4*8*512)
#define NEXP 257

#define OFF_B16    0u           // bf16 blob
#define OFF_B32    13107200u    // f32 blob
#define OFF_FLAG   19922944u    // dtype flag
#define OFF_SFLAGS 19923200u    // 64 uint scan flags
#define OFF_A      19923968u    // 256*256 f32
#define OFF_BD     20972544u    // 256 f32
#define OFF_APRE   20973568u    // 8*1024 f32
#define OFF_ACTB   21006336u    // 8192*512 bf16
#define OFF_Q      29394944u    // 8192*512 bf16 (ctx aliases Q)
#define OFF_KV     37783552u    // K|V bf16 16MB; expm f64 + eo/cbuf/ys f32 alias
#define OFF_WMA    54560768u    // 512*260 f32 (col 256 = WmB)
#define OFF_S12    55093504u    // 2*8*16 f32
#define OFF_HB     55094528u    // 2*8*512 f32
#define OFF_MB     55127296u    // 2*8*256 f32
// total ~52.6 MB

// ---------------- dtype sniffer --------------------------------------------
__global__ __launch_bounds__(64) void k_sniff(const ushort* x, uint* flag) {
    int i = threadIdx.x;
    ushort u = x[2 * i];
    uint e = (u >> 7) & 0xffu;
    bool ok = (u == 0) || (e >= 100u && e <= 140u);
    unsigned long long m = __ballot(ok);
    if (i == 0) *flag = (m == ~0ull) ? 0u : 1u;   // 0 = bf16 inputs, 1 = f32
}

__global__ __launch_bounds__(256) void k_cvt16(const void* src, ushort* dst, int n,
                                               const uint* flag) {
    int i = blockIdx.x * 256 + threadIdx.x;
    if (i >= n) return;
    dst[i] = (*flag) ? f2bf(((const float*)src)[i]) : ((const ushort*)src)[i];
}
__global__ __launch_bounds__(256) void k_cvt32(const void* src, float* dst, int n,
                                               const uint* flag) {
    int i = blockIdx.x * 256 + threadIdx.x;
    if (i >= n) return;
    dst[i] = (*flag) ? ((const float*)src)[i] : bf2f(((const ushort*)src)[i]);
}

// ---------------- device expm (LegS, f64) ----------------------------------
__global__ __launch_bounds__(256) void k_expm_init(double* M, double* T, uint* sflags) {
    int idx = blockIdx.x * 256 + threadIdx.x;
    if (idx < 64) sflags[idx] = 0u;
    if (idx >= NEXP * NEXP) return;
    int i = idx / NEXP, j = idx - i * NEXP;
    double v = 0.0;
    if (i < 256) {
        double R = (2.0 * i + 1.0) / 128.0;
        if (j < 256) v = ((i < j) ? -1.0 : (((i - j) & 1) ? 1.0 : -1.0)) * R;
        else         v = ((i & 1) ? -1.0 : 1.0) * R;
    }
    M[idx] = v * (1.0 / 2048.0);
    T[idx] = (i == j) ? 1.0 : 0.0;
}

__global__ __launch_bounds__(256) void k_expm_mul(const double* M, const double* src,
                                                  double* dst, int k) {
    int idx = blockIdx.x * 256 + threadIdx.x;
    if (idx >= NEXP * NEXP) return;
    int i = idx / NEXP, j = idx - i * NEXP;
    const double* a = (k ? M : src) + (size_t)i * NEXP;
    double acc = 0.0;
    for (int l = 0; l < NEXP; l++) acc += a[l] * src[(size_t)l * NEXP + j];
    dst[idx] = k ? (acc / (double)k + ((i == j) ? 1.0 : 0.0)) : acc;
}

__global__ __launch_bounds__(256) void k_expm_extract(const double* P, float* A, float* B) {
    int idx = blockIdx.x * 256 + threadIdx.x;
    if (idx >= 256 * 256) return;
    int i = idx >> 8, j = idx & 255;
    A[idx] = (float)P[(size_t)i * NEXP + j];
    if (j == 0) B[i] = (float)P[(size_t)i * NEXP + 256];
}

// ---------------- network kernels ------------------------------------------

__global__ __launch_bounds__(256) void k_in_proj(const ushort* __restrict__ x,
                                                 const ushort* __restrict__ W,
                                                 const ushort* __restrict__ bias,
                                                 ushort* __restrict__ outb) {
    int gid = blockIdx.x * 256 + threadIdx.x;
    int n = gid & 511;
    int row = gid >> 9;
    const ushort* xr = x + row * DIN;
    const ushort* wr = W + n * DIN;
    float acc = bf2f(bias[n]);
#pragma unroll
    for (int k = 0; k < DIN; k++) acc += bf2f(xr[k]) * bf2f(wr[k]);
    outb[gid] = f2bf(acc);
}

// C[M][N] = A[M][K] @ W[N][K]^T (+bias). dual: f32 if *dual else bf16.
__global__ __launch_bounds__(256) void k_gemm(const ushort* A,
                                              const ushort* W,
                                              const ushort* bias,
                                              float* outf,
                                              ushort* outb,
                                              int M, int N, int K,
                                              const uint* dual) {
    int tn = blockIdx.x * 64;
    int tm = blockIdx.y * 64;
    int wave = threadIdx.x >> 6;
    int lane = threadIdx.x & 63;
    int l16 = lane & 15, q = lane >> 4;
    uint fl = dual ? *dual : 2u;
    const ushort* arow = A + (size_t)(tm + wave * 16 + l16) * K + q * 8;
    const ushort* w0 = W + (size_t)(tn + 0 + l16) * K + q * 8;
    const ushort* w1 = W + (size_t)(tn + 16 + l16) * K + q * 8;
    const ushort* w2 = W + (size_t)(tn + 32 + l16) * K + q * 8;
    const ushort* w3 = W + (size_t)(tn + 48 + l16) * K + q * 8;
    f32x4 acc[4];
#pragma unroll
    for (int j = 0; j < 4; j++) acc[j] = (f32x4){0.f, 0.f, 0.f, 0.f};
    for (int kk = 0; kk < K; kk += 32) {
        short8 a = *(const short8*)(arow + kk);
        short8 b0 = *(const short8*)(w0 + kk);
        short8 b1 = *(const short8*)(w1 + kk);
        short8 b2 = *(const short8*)(w2 + kk);
        short8 b3 = *(const short8*)(w3 + kk);
        acc[0] = __builtin_amdgcn_mfma_f32_16x16x32_bf16(a, b0, acc[0], 0, 0, 0);
        acc[1] = __builtin_amdgcn_mfma_f32_16x16x32_bf16(a, b1, acc[1], 0, 0, 0);
        acc[2] = __builtin_amdgcn_mfma_f32_16x16x32_bf16(a, b2, acc[2], 0, 0, 0);
        acc[3] = __builtin_amdgcn_mfma_f32_16x16x32_bf16(a, b3, acc[3], 0, 0, 0);
    }
#pragma unroll
    for (int j = 0; j < 4; j++) {
        int col = tn + j * 16 + l16;
        float bv = bias ? bf2f(bias[col]) : 0.f;
#pragma unroll
        for (int i = 0; i < 4; i++) {
            int m = tm + wave * 16 + q * 4 + i;
            float v = acc[j][i] + bv;
            size_t off = (size_t)m * N + col;
            if (fl == 2u) {
                if (outf) outf[off] = v;
                if (outb) outb[off] = f2bf(v);
            } else if (fl == 1u) {
                outf[off] = v;
            } else {
                outb[off] = f2bf(v);
            }
        }
    }
}

// flash attention: grid (T/64, B*NH); 64 q-rows per block, wave w owns rows
// w*16..+15. ctx MAY EQUAL Qg (Q staged to LDS before any write; disjoint
// regions across blocks).
#define FAP 72
__global__ __launch_bounds__(256) void k_flash(const ushort* Qg,
                                               const ushort* Kg,
                                               const ushort* Vg,
                                               ushort* ctx) {
    __shared__ ushort Qs[64 * FAP], Ks[64 * FAP], Vr[64 * FAP], Vt[64 * FAP];
    __shared__ ushort Ps[4][16 * FAP];
    int qb = blockIdx.x * 64;
    int bh = blockIdx.y;
    int b = bh >> 3, h = bh & 7;
    int tid = threadIdx.x;
    int wave = tid >> 6, lane = tid & 63, l16 = lane & 15, qd = lane >> 4;
    const ushort* Qp = Qg + (size_t)(b * 1024) * 512 + h * 64;
    const ushort* Kp = Kg + (size_t)(b * 1024) * 512 + h * 64;
    const ushort* Vp = Vg + (size_t)(b * 1024) * 512 + h * 64;
    {
        int row = tid >> 2, seg = tid & 3;
        const uint4* src = (const uint4*)(Qp + (size_t)(qb + row) * 512 + seg * 16);
        *(uint4*)&Qs[row * FAP + seg * 16] = src[0];
        *(uint4*)&Qs[row * FAP + seg * 16 + 8] = src[1];
    }
    float run_m[4], run_l[4];
    f32x4 Of[4];
#pragma unroll
    for (int i = 0; i < 4; i++) { run_m[i] = -1e30f; run_l[i] = 0.f; }
#pragma unroll
    for (int j = 0; j < 4; j++) Of[j] = (f32x4){0.f, 0.f, 0.f, 0.f};

    for (int kb = 0; kb < 16; kb++) {
        int k0 = kb * 64;
        __syncthreads();
        {
            int row = tid >> 2, seg = tid & 3;
            const uint4* ks = (const uint4*)(Kp + (size_t)(k0 + row) * 512 + seg * 16);
            *(uint4*)&Ks[row * FAP + seg * 16] = ks[0];
            *(uint4*)&Ks[row * FAP + seg * 16 + 8] = ks[1];
            const uint4* vs = (const uint4*)(Vp + (size_t)(k0 + row) * 512 + seg * 16);
            *(uint4*)&Vr[row * FAP + seg * 16] = vs[0];
            *(uint4*)&Vr[row * FAP + seg * 16 + 8] = vs[1];
        }
        __syncthreads();
#pragma unroll
        for (int it = 0; it < 16; it++) {           // Vt[d][kv] = Vr[kv][d]
            int linear = it * 256 + tid;
            int d = linear & 63;
            int kv = linear >> 6;
            Vt[d * FAP + kv] = Vr[kv * FAP + d];
        }
        __syncthreads();
        f32x4 s[4];
#pragma unroll
        for (int j = 0; j < 4; j++) s[j] = (f32x4){0.f, 0.f, 0.f, 0.f};
#pragma unroll
        for (int j = 0; j < 4; j++) {
#pragma unroll
            for (int kk = 0; kk < 2; kk++) {
                short8 a = *(const short8*)&Qs[(wave * 16 + l16) * FAP + kk * 32 + qd * 8];
                short8 bb = *(const short8*)&Ks[(j * 16 + l16) * FAP + kk * 32 + qd * 8];
                s[j] = __builtin_amdgcn_mfma_f32_16x16x32_bf16(a, bb, s[j], 0, 0, 0);
            }
        }
#pragma unroll
        for (int i = 0; i < 4; i++) {
            float mx = -1e30f;
#pragma unroll
            for (int j = 0; j < 4; j++) { s[j][i] *= 0.125f; mx = fmaxf(mx, s[j][i]); }
#pragma unroll
            for (int off = 1; off < 16; off <<= 1) mx = fmaxf(mx, __shfl_xor(mx, off, 64));
            float nm = fmaxf(run_m[i], mx);
            float al = __expf(run_m[i] - nm);
            float rs = 0.f;
#pragma unroll
            for (int j = 0; j < 4; j++) { s[j][i] = __expf(s[j][i] - nm); rs += s[j][i]; }
#pragma unroll
            for (int off = 1; off < 16; off <<= 1) rs += __shfl_xor(rs, off, 64);
            run_l[i] = run_l[i] * al + rs;
            run_m[i] = nm;
#pragma unroll
            for (int j = 0; j < 4; j++) Of[j][i] *= al;
        }
#pragma unroll
        for (int j = 0; j < 4; j++)
#pragma unroll
            for (int i = 0; i < 4; i++)
                Ps[wave][(qd * 4 + i) * FAP + j * 16 + l16] = f2bf(s[j][i]);
#pragma unroll
        for (int j = 0; j < 4; j++) {
#pragma unroll
            for (int kk = 0; kk < 2; kk++) {
                short8 a = *(const short8*)&Ps[wave][l16 * FAP + kk * 32 + qd * 8];
                short8 bb = *(const short8*)&Vt[(j * 16 + l16) * FAP + kk * 32 + qd * 8];
                Of[j] = __builtin_amdgcn_mfma_f32_16x16x32_bf16(a, bb, Of[j], 0, 0, 0);
            }
        }
    }
#pragma unroll
    for (int i = 0; i < 4; i++) {
        float iv = 1.0f / run_l[i];
#pragma unroll
        for (int j = 0; j < 4; j++) {
            int row = qb + wave * 16 + qd * 4 + i;
            int col = h * 64 + j * 16 + l16;
            ctx[(size_t)(b * 1024 + row) * 512 + col] = f2bf(Of[j][i] * iv);
        }
    }
}

// LayerNorm over 512; optional bf16 residual; bf16 out. resb MAY EQUAL outb.
__global__ __launch_bounds__(256) void k_ln(const float* x,
                                            const ushort* resb,
                                            const ushort* __restrict__ g,
                                            const ushort* __restrict__ bb,
                                            ushort* outb,
                                            int useRes) {
    int row = blockIdx.x * 4 + (threadIdx.x >> 6);
    int lane = threadIdx.x & 63;
    const float* xr = x + (size_t)row * 512;
    const ushort* rr = resb + (size_t)row * 512;
    float v[8];
    float s = 0.f, sq = 0.f;
#pragma unroll
    for (int j = 0; j < 8; j++) {
        float t = xr[lane + 64 * j];
        if (useRes) t += bf2f(rr[lane + 64 * j]);
        v[j] = t; s += t;
    }
#pragma unroll
    for (int j = 0; j < 8; j++) sq += v[j] * v[j];
#pragma unroll
    for (int off = 32; off; off >>= 1) { s += __shfl_xor(s, off, 64); sq += __shfl_xor(sq, off, 64); }
    float mu = s * (1.f / 512.f);
    float var = sq * (1.f / 512.f) - mu * mu;
    float rstd = rsqrtf(var + 1e-5f);
#pragma unroll
    for (int j = 0; j < 8; j++) {
        int c = lane + 64 * j;
        float y = (v[j] - mu) * rstd * bf2f(g[c]) + bf2f(bb[c]);
        outb[(size_t)row * 512 + c] = f2bf(y);
    }
}

__global__ __launch_bounds__(256) void k_apre(const ushort* __restrict__ x,
                                              const ushort* __restrict__ ex,
                                              float* __restrict__ out) {
    int row = blockIdx.x * 4 + (threadIdx.x >> 6);
    int lane = threadIdx.x & 63;
    float s = 0.f;
#pragma unroll
    for (int j = 0; j < 8; j++) s += bf2f(x[(size_t)row * 512 + lane + 64 * j]) * bf2f(ex[lane + 64 * j]);
#pragma unroll
    for (int off = 32; off; off >>= 1) s += __shfl_xor(s, off, 64);
    if (lane == 0) out[row] = s;
}

// WmA[j][k] = sum_l Wm[j][l]*A[l][k] (k<256); col 256 = Wm@B. stride 260. f32.
__global__ __launch_bounds__(256) void k_wma(const float* __restrict__ Wm,
                                             const float* __restrict__ A,
                                             const float* __restrict__ Bd,
                                             float* __restrict__ out) {
    int j = blockIdx.x;
    int k = blockIdx.y * 256 + threadIdx.x;
    if (k >= 257) return;
    float acc = 0.f;
    for (int l = 0; l < 256; l++) {
        float w = Wm[j * 256 + l];
        float av = (k < 256) ? A[l * 256 + k] : Bd[l];
        acc += w * av;
    }
    out[j * 260 + k] = acc;
}

DEVINL float tanh_fast(float x) {
    float e = __expf(-2.f * fabsf(x));
    float th = (1.f - e) / (1.f + e);
    return copysignf(th, x);
}

// Fast LMU scan: 64 blocks, 256 threads. b = blockIdx&7 so one batch's 8 WGs
// land on one XCD (empirical blk%8->XCD map; perf heuristic only — agent
// scope keeps it correct regardless). Weights in VGPRs; flags monotonic.
__global__ __launch_bounds__(256, 2) void k_scan(
    const float* __restrict__ Whp,    // [512][512] f32 (layer slice)
    const float* __restrict__ WmA,    // [512][260] f32, col256 = WmB
    const float* __restrict__ Ac,     // [256][256] f32
    const float* __restrict__ Bd,     // [256] f32
    const float* __restrict__ ehp,    // [512] f32
    const float* __restrict__ emp,    // [256] f32
    const float* cg,                  // [8][1024][512] Wx@x
    const float* __restrict__ apre,   // [8][1024]
    float* ys,                        // [8][1024][512] (may == cg)
    float* Hbuf,                      // [2][8][512]
    float* Mbuf,                      // [2][8][256]
    float* S12,                       // [2][8][16]
    uint* flags,                      // [8][8]
    void* outbase,
    int hsL, int msL,
    int layer,
    const uint* dual) {
    const int tid = threadIdx.x;
    const int b = blockIdx.x & 7, g = blockIdx.x >> 3;   // XCD-colocate per batch
    const int r = tid & 63, s = tid >> 6;
    const int rz = tid & 31, sz = tid >> 5;
    __shared__ float h_s[512], m_s[256], red[256], red2[256], up[16], ehs[64], ems[32];
    __shared__ float A_lds[32 * 260];
    const uint fl = *dual;

    float wh[128];   // Wh row (g*64+r), cols s*128 .. +127
    {
        const float* pw = Whp + (size_t)(g * 64 + r) * 512 + s * 128;
#pragma unroll
        for (int i = 0; i < 32; i++) {
            float4 v = *(const float4*)(pw + i * 4);
            wh[i * 4 + 0] = v.x; wh[i * 4 + 1] = v.y; wh[i * 4 + 2] = v.z; wh[i * 4 + 3] = v.w;
        }
    }
    float wma[64];   // WmA row (g*64+r), cols s*64 .. +63
    {
        const float* p = WmA + (size_t)(g * 64 + r) * 260 + s * 64;
#pragma unroll
        for (int i = 0; i < 16; i++) {
            float4 v = *(const float4*)(p + i * 4);
            wma[i * 4 + 0] = v.x; wma[i * 4 + 1] = v.y; wma[i * 4 + 2] = v.z; wma[i * 4 + 3] = v.w;
        }
    }
    float wmb = WmA[(size_t)(g * 64 + r) * 260 + 256];
    float bdv = Bd[g * 32 + rz];
#pragma unroll
    for (int i = 0; i < 8; i++) {
        int idx4 = i * 256 + tid;
        int row = idx4 >> 6;
        int c4 = (idx4 & 63) * 4;
        *(float4*)&A_lds[row * 260 + c4] = *(const float4*)&Ac[(size_t)(g * 32 + row) * 256 + c4];
    }
    if (tid < 64) ehs[tid] = ehp[g * 64 + tid];
    if (tid >= 64 && tid < 96) ems[tid - 64] = emp[g * 32 + (tid - 64)];
    __syncthreads();

    uint* myflags = flags + b * 8;
    const float* crow = cg + (size_t)(b * 1024) * 512 + g * 64;
    const float* arow = apre + b * 1024;
    float* ysrow = ys + (size_t)(b * 1024) * 512 + g * 64;

    for (int t = 1; t <= 1024; ++t) {
        const int pp = (t - 1) & 1, cp = t & 1;
        float cpre = (tid < 64) ? crow[(size_t)(t - 1) * 512 + tid] : 0.f;
        float av = arow[t - 1];
        if (t == 1) {
            float4 zz = {0.f, 0.f, 0.f, 0.f};
            if (tid < 128) *(float4*)&h_s[tid * 4] = zz;
            else if (tid < 192) *(float4*)&m_s[(tid - 128) * 4] = zz;
            if (tid < 16) up[tid] = 0.f;
            __syncthreads();
        } else {
            const uint target = (uint)(layer * 1024 + t - 1);
            if (tid < 8) {
                int guard = 0;
                while (__hip_atomic_load(&myflags[tid], __ATOMIC_RELAXED, __HIP_MEMORY_SCOPE_AGENT) < target
                       && ++guard < (1 << 27)) {}
            }
            __syncthreads();
            __builtin_amdgcn_fence(__ATOMIC_ACQUIRE, "agent");
            if (tid < 128) {
#pragma unroll
                for (int k = 0; k < 4; k++)
                    h_s[tid * 4 + k] = atomLoad(&Hbuf[(pp * 8 + b) * 512 + tid * 4 + k]);
            } else if (tid < 192) {
                int i = tid - 128;
#pragma unroll
                for (int k = 0; k < 4; k++)
                    m_s[i * 4 + k] = atomLoad(&Mbuf[(pp * 8 + b) * 256 + i * 4 + k]);
            } else if (tid < 208) {
                up[tid - 192] = atomLoad(&S12[(pp * 8 + b) * 16 + (tid - 192)]);
            }
            __syncthreads();
        }
        float u = av;
#pragma unroll
        for (int i = 0; i < 16; i++) u += up[i];

        float a0 = 0.f, a1 = 0.f, a2 = 0.f, a3 = 0.f;
        {
            const float* hp = &h_s[s * 128];
#pragma unroll
            for (int k4 = 0; k4 < 32; k4++) {
                float4 hv = *(const float4*)&hp[k4 * 4];
                a0 += wh[k4 * 4 + 0] * hv.x; a1 += wh[k4 * 4 + 1] * hv.y;
                a2 += wh[k4 * 4 + 2] * hv.z; a3 += wh[k4 * 4 + 3] * hv.w;
            }
            const float* mp = &m_s[s * 64];
#pragma unroll
            for (int k4 = 0; k4 < 16; k4++) {
                float4 mv = *(const float4*)&mp[k4 * 4];
                a0 += wma[k4 * 4 + 0] * mv.x; a1 += wma[k4 * 4 + 1] * mv.y;
                a2 += wma[k4 * 4 + 2] * mv.z; a3 += wma[k4 * 4 + 3] * mv.w;
            }
        }
        float qa = (a0 + a1) + (a2 + a3);
        float z0 = 0.f, z1 = 0.f, z2 = 0.f, z3 = 0.f;
        {
            const float* ap = &A_lds[rz * 260 + sz * 32];
            const float* mp = &m_s[sz * 32];
#pragma unroll
            for (int k4 = 0; k4 < 8; k4++) {
                float4 avv = *(const float4*)&ap[k4 * 4];
                float4 mvv = *(const float4*)&mp[k4 * 4];
                z0 += avv.x * mvv.x; z1 += avv.y * mvv.y; z2 += avv.z * mvv.z; z3 += avv.w * mvv.w;
            }
        }
        float za = (z0 + z1) + (z2 + z3);
        red[r * 4 + s] = qa;
        red2[rz * 8 + sz] = za;
        __syncthreads();

        float hn = 0.f, mn = 0.f;
        if (tid < 64) {
            float4 rv = *(const float4*)&red[tid * 4];
            float pre = cpre + u * wmb + (rv.x + rv.y) + (rv.z + rv.w);
            hn = tanh_fast(pre);
            atomStore(&Hbuf[(cp * 8 + b) * 512 + g * 64 + tid], hn);
            ysrow[(size_t)(t - 1) * 512 + tid] = hn;
            float pe = ehs[tid] * hn;
#pragma unroll
            for (int off = 32; off; off >>= 1) pe += __shfl_xor(pe, off, 64);
            if (tid == 0) atomStore(&S12[(cp * 8 + b) * 16 + g], pe);
        } else if (tid < 96) {
            int i = tid - 64;
            float4 r0 = *(const float4*)&red2[i * 8];
            float4 r1 = *(const float4*)&red2[i * 8 + 4];
            mn = ((r0.x + r0.y) + (r0.z + r0.w)) + ((r1.x + r1.y) + (r1.z + r1.w)) + u * bdv;
            atomStore(&Mbuf[(cp * 8 + b) * 256 + g * 32 + i], mn);
            float pe = ems[i] * mn;
#pragma unroll
            for (int off = 16; off; off >>= 1) pe += __shfl_xor(pe, off, 64);
            if (i == 0) atomStore(&S12[(cp * 8 + b) * 16 + 8 + g], pe);
        }
        if (t == 1024) {
            if (fl) {
                float* ob = (float*)outbase;
                if (tid < 64) ob[hsL + b * 512 + g * 64 + tid] = hn;
                else if (tid < 96) ob[msL + b * 256 + g * 32 + (tid - 64)] = mn;
            } else {
                ushort* ob = (ushort*)outbase;
                if (tid < 64) ob[hsL + b * 512 + g * 64 + tid] = f2bf(hn);
                else if (tid < 96) ob[msL + b * 256 + g * 32 + (tid - 64)] = f2bf(mn);
            }
        }
        __syncthreads();
        if (tid == 0)
            __hip_atomic_store(&myflags[g], (uint)(layer * 1024 + t), __ATOMIC_RELEASE, __HIP_MEMORY_SCOPE_AGENT);
    }
}

// ---------------- launch ---------------------------------------------------
extern "C" void kernel_launch(void* const* d_in, const int* in_sizes, int n_in,
                              void* d_out, int out_size, void* d_ws, size_t ws_size,
                              hipStream_t stream) {
    char* ws = (char*)d_ws;
    uint* flag = (uint*)(ws + OFF_FLAG);
    uint* sflags = (uint*)(ws + OFF_SFLAGS);
    float* A_c = (float*)(ws + OFF_A);
    float* B_c = (float*)(ws + OFF_BD);
    float* apre = (float*)(ws + OFF_APRE);
    float* WmAb = (float*)(ws + OFF_WMA);
    float* S12f = (float*)(ws + OFF_S12);
    float* Hb = (float*)(ws + OFF_HB);
    float* Mb = (float*)(ws + OFF_MB);
    ushort* actb = (ushort*)(ws + OFF_ACTB);
    ushort* qb_ = (ushort*)(ws + OFF_Q);
    ushort* kb_ = (ushort*)(ws + OFF_KV);
    ushort* vb_ = (ushort*)(ws + OFF_KV + 8388608u);
    ushort* ctx = qb_;
    float* eo = (float*)(ws + OFF_KV);
    float* cbuf = eo;
    float* ysb = cbuf;
    double* Mm = (double*)(ws + OFF_KV);
    double* Tt = (double*)(ws + OFF_KV + 528640u);
    double* Pp = (double*)(ws + OFF_KV + 1057280u);

    k_sniff<<<1, 64, 0, stream>>>((const ushort*)d_in[0], flag);

    static const int isF32[23] = {0,0,0, 0,0,0,0,0,0,0,0, 0,0, 0,1,1, 0,1,1, 0,0,0,0};
    const void* cp[23];
    {
        size_t o16 = 0, o32 = 0;
        for (int i = 0; i < 23; i++) {
            int n = in_sizes[i];
            if (isF32[i]) {
                float* dst = (float*)(ws + OFF_B32 + o32 * 4);
                k_cvt32<<<(n + 255) / 256, 256, 0, stream>>>(d_in[i], dst, n, flag);
                cp[i] = dst;
                o32 += (size_t)((n + 127) & ~127);
            } else {
                ushort* dst = (ushort*)(ws + OFF_B16 + o16 * 2);
                k_cvt16<<<(n + 255) / 256, 256, 0, stream>>>(d_in[i], dst, n, flag);
                cp[i] = dst;
                o16 += (size_t)((n + 127) & ~127);
            }
        }
    }
    const ushort* xb    = (const ushort*)cp[0];
    const ushort* W_in  = (const ushort*)cp[1];
    const ushort* b_in  = (const ushort*)cp[2];
    const ushort* Wq    = (const ushort*)cp[3];
    const ushort* bq    = (const ushort*)cp[4];
    const ushort* Wk    = (const ushort*)cp[5];
    const ushort* bk    = (const ushort*)cp[6];
    const ushort* Wv    = (const ushort*)cp[7];
    const ushort* bv    = (const ushort*)cp[8];
    const ushort* Wo    = (const ushort*)cp[9];
    const ushort* bo    = (const ushort*)cp[10];
    const ushort* g_at  = (const ushort*)cp[11];
    const ushort* b_at  = (const ushort*)cp[12];
    const ushort* e_x   = (const ushort*)cp[13];
    const float*  e_h   = (const float*)cp[14];
    const float*  e_m   = (const float*)cp[15];
    const ushort* Wx    = (const ushort*)cp[16];
    const float*  Wh    = (const float*)cp[17];
    const float*  Wm    = (const float*)cp[18];
    const ushort* g_lnp = (const ushort*)cp[19];
    const ushort* b_lnp = (const ushort*)cp[20];
    const ushort* W_out = (const ushort*)cp[21];
    const ushort* b_out = (const ushort*)cp[22];

    k_expm_init<<<259, 256, 0, stream>>>(Mm, Tt, sflags);
    double* cur = Tt; double* oth = Pp;
    for (int k = 20; k >= 1; k--) {
        k_expm_mul<<<259, 256, 0, stream>>>(Mm, cur, oth, k);
        std::swap(cur, oth);
    }
    for (int r = 0; r < 11; r++) {
        k_expm_mul<<<259, 256, 0, stream>>>(Mm, cur, oth, 0);
        std::swap(cur, oth);
    }
    k_expm_extract<<<256, 256, 0, stream>>>(cur, A_c, B_c);

    k_in_proj<<<16384, 256, 0, stream>>>(xb, W_in, b_in, actb);

    dim3 gg(8, 128);
    for (int L = 0; L < NLAYER; L++) {
        const size_t wofs = (size_t)L * 512 * 512;
        k_gemm<<<gg, 256, 0, stream>>>(actb, Wq + wofs, bq + L * 512, nullptr, qb_, 8192, 512, 512, nullptr);
        k_gemm<<<gg, 256, 0, stream>>>(actb, Wk + wofs, bk + L * 512, nullptr, kb_, 8192, 512, 512, nullptr);
        k_gemm<<<gg, 256, 0, stream>>>(actb, Wv + wofs, bv + L * 512, nullptr, vb_, 8192, 512, 512, nullptr);
        k_flash<<<dim3(16, 64), 256, 0, stream>>>(qb_, kb_, vb_, ctx);
        k_gemm<<<gg, 256, 0, stream>>>(ctx, Wo + wofs, bo + L * 512, eo, nullptr, 8192, 512, 512, nullptr);
        k_ln<<<2048, 256, 0, stream>>>(eo, actb, g_at + L * 512, b_at + L * 512, actb, 1);
        k_wma<<<dim3(512, 2), 256, 0, stream>>>(Wm + (size_t)L * 512 * 256, A_c, B_c, WmAb);
        k_apre<<<2048, 256, 0, stream>>>(actb, e_x + L * 512, apre);
        k_gemm<<<gg, 256, 0, stream>>>(actb, Wx + wofs, nullptr, cbuf, nullptr, 8192, 512, 512, nullptr);
        k_scan<<<64, 256, 0, stream>>>(Wh + wofs, WmAb, A_c, B_c,
                                       e_h + L * 512, e_m + L * 256,
                                       cbuf, apre, ysb,
                                       Hb, Mb, S12f, sflags,
                                       d_out, HS_OFF + L * 4096, MS_OFF + L * 2048,
                                       L, flag);
        k_ln<<<2048, 256, 0, stream>>>(ysb, actb, g_lnp + L * 512, b_lnp + L * 512, actb, 0);
    }
    k_gemm<<<gg, 256, 0, stream>>>(actb, W_out, b_out, (float*)d_out, (ushort*)d_out, 8192, 512, 512, flag);
}

// Round 9
// 18770.012 us; speedup vs baseline: 11.7613x; 1.4478x over previous
//
#include <hip/hip_runtime.h>
#include <utility>

// ---------------------------------------------------------------------------
// LMUEncoder on MI355X — versioned-atomic scan exchange (no fences/flags).
// Inputs f32 (dtype-sniffed, canonicalized: bf16 for GEMM/attn, f32 for scan).
// Scan: 64 WGs (8/batch, XCD-colocated via b=blockIdx&7), weights in VGPRs;
// cross-WG state as (version<<32|f32bits) 64-bit relaxed agent atomics —
// readers poll data words directly; 2-parity buffering makes races impossible.
// B=8, T=1024, D_IN=80, H=512, MEM=256, L=4, NH=8, dk=64.
// ---------------------------------------------------------------------------

typedef unsigned int uint;
typedef unsigned short ushort;
typedef unsigned long long ull;
typedef __attribute__((ext_vector_type(8))) short short8;
typedef __attribute__((ext_vector_type(4))) float f32x4;

#define DEVINL static __device__ __forceinline__

DEVINL float bf2f(ushort u) { uint x = ((uint)u) << 16; float f; __builtin_memcpy(&f, &x, 4); return f; }
DEVINL ushort f2bf(float f) {
    uint u; __builtin_memcpy(&u, &f, 4);
    uint r = (u + 0x7fffu + ((u >> 16) & 1u)) >> 16;
    return (ushort)r;
}

DEVINL ull vload(const ull* p) {
    return __hip_atomic_load(p, __ATOMIC_RELAXED, __HIP_MEMORY_SCOPE_AGENT);
}
DEVINL void vstore(ull* p, ull v) {
    __hip_atomic_store(p, v, __ATOMIC_RELAXED, __HIP_MEMORY_SCOPE_AGENT);
}
DEVINL ull packv(float f, uint ver) { uint b; __builtin_memcpy(&b, &f, 4); return ((ull)ver << 32) | (ull)b; }
DEVINL float unpackv(ull v) { uint b = (uint)v; float f; __builtin_memcpy(&f, &b, 4); return f; }

// ---------------- sizes / ws layout (bytes, 256-aligned) -------------------
#define DIN 80
#define NLAYER 4
#define ENC_SZ (8*1024*512)
#define HS_OFF ENC_SZ
#define MS_OFF (ENC_SZ + 4*8*512)
#define NEXP 257

#define OFF_B16    0u           // bf16 blob
#define OFF_B32    13107200u    // f32 blob
#define OFF_FLAG   19922944u    // dtype flag
#define OFF_A      19923968u    // 256*256 f32
#define OFF_BD     20972544u    // 256 f32
#define OFF_APRE   20973568u    // 8*1024 f32
#define OFF_ACTB   21006336u    // 8192*512 bf16
#define OFF_Q      29394944u    // 8192*512 bf16 (ctx aliases Q)
#define OFF_KV     37783552u    // K|V bf16 16MB; expm f64 + eo/cbuf/ys f32 alias
#define OFF_WMA    54560768u    // 512*260 f32 (col 256 = WmB)
#define OFF_HV     55093504u    // ull[2][8][512] = 65536
#define OFF_MV     55159040u    // ull[2][8][256] = 32768
#define OFF_UV     55191808u    // ull[2][8][16]  = 2048
// total 55193856 ~ 52.6 MB. HV|MV|UV contiguous (zeroed together: 12544 ull).

// ---------------- dtype sniffer --------------------------------------------
__global__ __launch_bounds__(64) void k_sniff(const ushort* x, uint* flag) {
    int i = threadIdx.x;
    ushort u = x[2 * i];
    uint e = (u >> 7) & 0xffu;
    bool ok = (u == 0) || (e >= 100u && e <= 140u);
    unsigned long long m = __ballot(ok);
    if (i == 0) *flag = (m == ~0ull) ? 0u : 1u;   // 0 = bf16 inputs, 1 = f32
}

__global__ __launch_bounds__(256) void k_cvt16(const void* src, ushort* dst, int n,
                                               const uint* flag) {
    int i = blockIdx.x * 256 + threadIdx.x;
    if (i >= n) return;
    dst[i] = (*flag) ? f2bf(((const float*)src)[i]) : ((const ushort*)src)[i];
}
__global__ __launch_bounds__(256) void k_cvt32(const void* src, float* dst, int n,
                                               const uint* flag) {
    int i = blockIdx.x * 256 + threadIdx.x;
    if (i >= n) return;
    dst[i] = (*flag) ? ((const float*)src)[i] : bf2f(((const ushort*)src)[i]);
}

// ---------------- device expm (LegS, f64) ----------------------------------
// ||M||_1 = 512 -> scale 2^-11 (norm 0.25), Taylor-20 Horner, square x11.
// Also zeroes the 12544-ull versioned state block.
__global__ __launch_bounds__(256) void k_expm_init(double* M, double* T, ull* vstate) {
    int idx = blockIdx.x * 256 + threadIdx.x;
    if (idx < 12544) vstate[idx] = 0ull;
    if (idx >= NEXP * NEXP) return;
    int i = idx / NEXP, j = idx - i * NEXP;
    double v = 0.0;
    if (i < 256) {
        double R = (2.0 * i + 1.0) / 128.0;
        if (j < 256) v = ((i < j) ? -1.0 : (((i - j) & 1) ? 1.0 : -1.0)) * R;
        else         v = ((i & 1) ? -1.0 : 1.0) * R;
    }
    M[idx] = v * (1.0 / 2048.0);
    T[idx] = (i == j) ? 1.0 : 0.0;
}

__global__ __launch_bounds__(256) void k_expm_mul(const double* M, const double* src,
                                                  double* dst, int k) {
    int idx = blockIdx.x * 256 + threadIdx.x;
    if (idx >= NEXP * NEXP) return;
    int i = idx / NEXP, j = idx - i * NEXP;
    const double* a = (k ? M : src) + (size_t)i * NEXP;
    double acc = 0.0;
    for (int l = 0; l < NEXP; l++) acc += a[l] * src[(size_t)l * NEXP + j];
    dst[idx] = k ? (acc / (double)k + ((i == j) ? 1.0 : 0.0)) : acc;
}

__global__ __launch_bounds__(256) void k_expm_extract(const double* P, float* A, float* B) {
    int idx = blockIdx.x * 256 + threadIdx.x;
    if (idx >= 256 * 256) return;
    int i = idx >> 8, j = idx & 255;
    A[idx] = (float)P[(size_t)i * NEXP + j];
    if (j == 0) B[i] = (float)P[(size_t)i * NEXP + 256];
}

// ---------------- network kernels ------------------------------------------

__global__ __launch_bounds__(256) void k_in_proj(const ushort* __restrict__ x,
                                                 const ushort* __restrict__ W,
                                                 const ushort* __restrict__ bias,
                                                 ushort* __restrict__ outb) {
    int gid = blockIdx.x * 256 + threadIdx.x;
    int n = gid & 511;
    int row = gid >> 9;
    const ushort* xr = x + row * DIN;
    const ushort* wr = W + n * DIN;
    float acc = bf2f(bias[n]);
#pragma unroll
    for (int k = 0; k < DIN; k++) acc += bf2f(xr[k]) * bf2f(wr[k]);
    outb[gid] = f2bf(acc);
}

// C[M][N] = A[M][K] @ W[N][K]^T (+bias). dual: f32 if *dual else bf16.
__global__ __launch_bounds__(256) void k_gemm(const ushort* A,
                                              const ushort* W,
                                              const ushort* bias,
                                              float* outf,
                                              ushort* outb,
                                              int M, int N, int K,
                                              const uint* dual) {
    int tn = blockIdx.x * 64;
    int tm = blockIdx.y * 64;
    int wave = threadIdx.x >> 6;
    int lane = threadIdx.x & 63;
    int l16 = lane & 15, q = lane >> 4;
    uint fl = dual ? *dual : 2u;
    const ushort* arow = A + (size_t)(tm + wave * 16 + l16) * K + q * 8;
    const ushort* w0 = W + (size_t)(tn + 0 + l16) * K + q * 8;
    const ushort* w1 = W + (size_t)(tn + 16 + l16) * K + q * 8;
    const ushort* w2 = W + (size_t)(tn + 32 + l16) * K + q * 8;
    const ushort* w3 = W + (size_t)(tn + 48 + l16) * K + q * 8;
    f32x4 acc[4];
#pragma unroll
    for (int j = 0; j < 4; j++) acc[j] = (f32x4){0.f, 0.f, 0.f, 0.f};
    for (int kk = 0; kk < K; kk += 32) {
        short8 a = *(const short8*)(arow + kk);
        short8 b0 = *(const short8*)(w0 + kk);
        short8 b1 = *(const short8*)(w1 + kk);
        short8 b2 = *(const short8*)(w2 + kk);
        short8 b3 = *(const short8*)(w3 + kk);
        acc[0] = __builtin_amdgcn_mfma_f32_16x16x32_bf16(a, b0, acc[0], 0, 0, 0);
        acc[1] = __builtin_amdgcn_mfma_f32_16x16x32_bf16(a, b1, acc[1], 0, 0, 0);
        acc[2] = __builtin_amdgcn_mfma_f32_16x16x32_bf16(a, b2, acc[2], 0, 0, 0);
        acc[3] = __builtin_amdgcn_mfma_f32_16x16x32_bf16(a, b3, acc[3], 0, 0, 0);
    }
#pragma unroll
    for (int j = 0; j < 4; j++) {
        int col = tn + j * 16 + l16;
        float bv = bias ? bf2f(bias[col]) : 0.f;
#pragma unroll
        for (int i = 0; i < 4; i++) {
            int m = tm + wave * 16 + q * 4 + i;
            float v = acc[j][i] + bv;
            size_t off = (size_t)m * N + col;
            if (fl == 2u) {
                if (outf) outf[off] = v;
                if (outb) outb[off] = f2bf(v);
            } else if (fl == 1u) {
                outf[off] = v;
            } else {
                outb[off] = f2bf(v);
            }
        }
    }
}

// flash attention: grid (T/64, B*NH); wave w owns q-rows w*16..+15.
// ctx MAY EQUAL Qg (Q staged to LDS first; disjoint regions across blocks).
#define FAP 72
__global__ __launch_bounds__(256) void k_flash(const ushort* Qg,
                                               const ushort* Kg,
                                               const ushort* Vg,
                                               ushort* ctx) {
    __shared__ ushort Qs[64 * FAP], Ks[64 * FAP], Vr[64 * FAP], Vt[64 * FAP];
    __shared__ ushort Ps[4][16 * FAP];
    int qb = blockIdx.x * 64;
    int bh = blockIdx.y;
    int b = bh >> 3, h = bh & 7;
    int tid = threadIdx.x;
    int wave = tid >> 6, lane = tid & 63, l16 = lane & 15, qd = lane >> 4;
    const ushort* Qp = Qg + (size_t)(b * 1024) * 512 + h * 64;
    const ushort* Kp = Kg + (size_t)(b * 1024) * 512 + h * 64;
    const ushort* Vp = Vg + (size_t)(b * 1024) * 512 + h * 64;
    {
        int row = tid >> 2, seg = tid & 3;
        const uint4* src = (const uint4*)(Qp + (size_t)(qb + row) * 512 + seg * 16);
        *(uint4*)&Qs[row * FAP + seg * 16] = src[0];
        *(uint4*)&Qs[row * FAP + seg * 16 + 8] = src[1];
    }
    float run_m[4], run_l[4];
    f32x4 Of[4];
#pragma unroll
    for (int i = 0; i < 4; i++) { run_m[i] = -1e30f; run_l[i] = 0.f; }
#pragma unroll
    for (int j = 0; j < 4; j++) Of[j] = (f32x4){0.f, 0.f, 0.f, 0.f};

    for (int kb = 0; kb < 16; kb++) {
        int k0 = kb * 64;
        __syncthreads();
        {
            int row = tid >> 2, seg = tid & 3;
            const uint4* ks = (const uint4*)(Kp + (size_t)(k0 + row) * 512 + seg * 16);
            *(uint4*)&Ks[row * FAP + seg * 16] = ks[0];
            *(uint4*)&Ks[row * FAP + seg * 16 + 8] = ks[1];
            const uint4* vs = (const uint4*)(Vp + (size_t)(k0 + row) * 512 + seg * 16);
            *(uint4*)&Vr[row * FAP + seg * 16] = vs[0];
            *(uint4*)&Vr[row * FAP + seg * 16 + 8] = vs[1];
        }
        __syncthreads();
#pragma unroll
        for (int it = 0; it < 16; it++) {
            int linear = it * 256 + tid;
            int d = linear & 63;
            int kv = linear >> 6;
            Vt[d * FAP + kv] = Vr[kv * FAP + d];
        }
        __syncthreads();
        f32x4 s[4];
#pragma unroll
        for (int j = 0; j < 4; j++) s[j] = (f32x4){0.f, 0.f, 0.f, 0.f};
#pragma unroll
        for (int j = 0; j < 4; j++) {
#pragma unroll
            for (int kk = 0; kk < 2; kk++) {
                short8 a = *(const short8*)&Qs[(wave * 16 + l16) * FAP + kk * 32 + qd * 8];
                short8 bb = *(const short8*)&Ks[(j * 16 + l16) * FAP + kk * 32 + qd * 8];
                s[j] = __builtin_amdgcn_mfma_f32_16x16x32_bf16(a, bb, s[j], 0, 0, 0);
            }
        }
#pragma unroll
        for (int i = 0; i < 4; i++) {
            float mx = -1e30f;
#pragma unroll
            for (int j = 0; j < 4; j++) { s[j][i] *= 0.125f; mx = fmaxf(mx, s[j][i]); }
#pragma unroll
            for (int off = 1; off < 16; off <<= 1) mx = fmaxf(mx, __shfl_xor(mx, off, 64));
            float nm = fmaxf(run_m[i], mx);
            float al = __expf(run_m[i] - nm);
            float rs = 0.f;
#pragma unroll
            for (int j = 0; j < 4; j++) { s[j][i] = __expf(s[j][i] - nm); rs += s[j][i]; }
#pragma unroll
            for (int off = 1; off < 16; off <<= 1) rs += __shfl_xor(rs, off, 64);
            run_l[i] = run_l[i] * al + rs;
            run_m[i] = nm;
#pragma unroll
            for (int j = 0; j < 4; j++) Of[j][i] *= al;
        }
#pragma unroll
        for (int j = 0; j < 4; j++)
#pragma unroll
            for (int i = 0; i < 4; i++)
                Ps[wave][(qd * 4 + i) * FAP + j * 16 + l16] = f2bf(s[j][i]);
#pragma unroll
        for (int j = 0; j < 4; j++) {
#pragma unroll
            for (int kk = 0; kk < 2; kk++) {
                short8 a = *(const short8*)&Ps[wave][l16 * FAP + kk * 32 + qd * 8];
                short8 bb = *(const short8*)&Vt[(j * 16 + l16) * FAP + kk * 32 + qd * 8];
                Of[j] = __builtin_amdgcn_mfma_f32_16x16x32_bf16(a, bb, Of[j], 0, 0, 0);
            }
        }
    }
#pragma unroll
    for (int i = 0; i < 4; i++) {
        float iv = 1.0f / run_l[i];
#pragma unroll
        for (int j = 0; j < 4; j++) {
            int row = qb + wave * 16 + qd * 4 + i;
            int col = h * 64 + j * 16 + l16;
            ctx[(size_t)(b * 1024 + row) * 512 + col] = f2bf(Of[j][i] * iv);
        }
    }
}

// LayerNorm over 512; optional bf16 residual; bf16 out. resb MAY EQUAL outb.
__global__ __launch_bounds__(256) void k_ln(const float* x,
                                            const ushort* resb,
                                            const ushort* __restrict__ g,
                                            const ushort* __restrict__ bb,
                                            ushort* outb,
                                            int useRes) {
    int row = blockIdx.x * 4 + (threadIdx.x >> 6);
    int lane = threadIdx.x & 63;
    const float* xr = x + (size_t)row * 512;
    const ushort* rr = resb + (size_t)row * 512;
    float v[8];
    float s = 0.f, sq = 0.f;
#pragma unroll
    for (int j = 0; j < 8; j++) {
        float t = xr[lane + 64 * j];
        if (useRes) t += bf2f(rr[lane + 64 * j]);
        v[j] = t; s += t;
    }
#pragma unroll
    for (int j = 0; j < 8; j++) sq += v[j] * v[j];
#pragma unroll
    for (int off = 32; off; off >>= 1) { s += __shfl_xor(s, off, 64); sq += __shfl_xor(sq, off, 64); }
    float mu = s * (1.f / 512.f);
    float var = sq * (1.f / 512.f) - mu * mu;
    float rstd = rsqrtf(var + 1e-5f);
#pragma unroll
    for (int j = 0; j < 8; j++) {
        int c = lane + 64 * j;
        float y = (v[j] - mu) * rstd * bf2f(g[c]) + bf2f(bb[c]);
        outb[(size_t)row * 512 + c] = f2bf(y);
    }
}

__global__ __launch_bounds__(256) void k_apre(const ushort* __restrict__ x,
                                              const ushort* __restrict__ ex,
                                              float* __restrict__ out) {
    int row = blockIdx.x * 4 + (threadIdx.x >> 6);
    int lane = threadIdx.x & 63;
    float s = 0.f;
#pragma unroll
    for (int j = 0; j < 8; j++) s += bf2f(x[(size_t)row * 512 + lane + 64 * j]) * bf2f(ex[lane + 64 * j]);
#pragma unroll
    for (int off = 32; off; off >>= 1) s += __shfl_xor(s, off, 64);
    if (lane == 0) out[row] = s;
}

// WmA[j][k] = sum_l Wm[j][l]*A[l][k] (k<256); col 256 = Wm@B. stride 260. f32.
__global__ __launch_bounds__(256) void k_wma(const float* __restrict__ Wm,
                                             const float* __restrict__ A,
                                             const float* __restrict__ Bd,
                                             float* __restrict__ out) {
    int j = blockIdx.x;
    int k = blockIdx.y * 256 + threadIdx.x;
    if (k >= 257) return;
    float acc = 0.f;
    for (int l = 0; l < 256; l++) {
        float w = Wm[j * 256 + l];
        float av = (k < 256) ? A[l * 256 + k] : Bd[l];
        acc += w * av;
    }
    out[j * 260 + k] = acc;
}

DEVINL float tanh_fast(float x) {
    float e = __expf(-2.f * fabsf(x));
    float th = (1.f - e) / (1.f + e);
    return copysignf(th, x);
}

// Fast LMU scan, versioned-atomic exchange. 64 blocks, 256 threads.
// b = blockIdx&7 (XCD-colocate batch); weights in VGPRs; no fences.
__global__ __launch_bounds__(256, 2) void k_scan(
    const float* __restrict__ Whp,    // [512][512] f32 (layer slice)
    const float* __restrict__ WmA,    // [512][260] f32, col256 = WmB
    const float* __restrict__ Ac,     // [256][256] f32
    const float* __restrict__ Bd,     // [256] f32
    const float* __restrict__ ehp,    // [512] f32
    const float* __restrict__ emp,    // [256] f32
    const float* cg,                  // [8][1024][512] Wx@x
    const float* __restrict__ apre,   // [8][1024]
    float* ys,                        // [8][1024][512] (may == cg)
    ull* Hv,                          // [2][8][512] versioned
    ull* Mv,                          // [2][8][256] versioned
    ull* Uv,                          // [2][8][16] versioned
    void* outbase,
    int hsL, int msL,
    int layer,
    const uint* dual) {
    const int tid = threadIdx.x;
    const int b = blockIdx.x & 7, g = blockIdx.x >> 3;
    const int r = tid & 63, s = tid >> 6;
    const int rz = tid & 31, sz = tid >> 5;
    __shared__ float h_s[512], m_s[256], red[256], red2[256], up[16], ehs[64], ems[32];
    __shared__ float A_lds[32 * 260];
    const uint fl = *dual;

    float wh[128];   // Wh row (g*64+r), cols s*128 .. +127
    {
        const float* pw = Whp + (size_t)(g * 64 + r) * 512 + s * 128;
#pragma unroll
        for (int i = 0; i < 32; i++) {
            float4 v = *(const float4*)(pw + i * 4);
            wh[i * 4 + 0] = v.x; wh[i * 4 + 1] = v.y; wh[i * 4 + 2] = v.z; wh[i * 4 + 3] = v.w;
        }
    }
    float wma[64];   // WmA row (g*64+r), cols s*64 .. +63
    {
        const float* p = WmA + (size_t)(g * 64 + r) * 260 + s * 64;
#pragma unroll
        for (int i = 0; i < 16; i++) {
            float4 v = *(const float4*)(p + i * 4);
            wma[i * 4 + 0] = v.x; wma[i * 4 + 1] = v.y; wma[i * 4 + 2] = v.z; wma[i * 4 + 3] = v.w;
        }
    }
    float wmb = WmA[(size_t)(g * 64 + r) * 260 + 256];
    float bdv = Bd[g * 32 + rz];
#pragma unroll
    for (int i = 0; i < 8; i++) {
        int idx4 = i * 256 + tid;
        int row = idx4 >> 6;
        int c4 = (idx4 & 63) * 4;
        *(float4*)&A_lds[row * 260 + c4] = *(const float4*)&Ac[(size_t)(g * 32 + row) * 256 + c4];
    }
    if (tid < 64) ehs[tid] = ehp[g * 64 + tid];
    if (tid >= 64 && tid < 96) ems[tid - 64] = emp[g * 32 + (tid - 64)];
    __syncthreads();

    const float* crow = cg + (size_t)(b * 1024) * 512 + g * 64;
    const float* arow = apre + b * 1024;
    float* ysrow = ys + (size_t)(b * 1024) * 512 + g * 64;

    for (int t = 1; t <= 1024; ++t) {
        const int pp = (t - 1) & 1, cp = t & 1;
        float cpre = (tid < 64) ? crow[(size_t)(t - 1) * 512 + tid] : 0.f;
        float av = arow[t - 1];
        if (t == 1) {
            float4 zz = {0.f, 0.f, 0.f, 0.f};
            if (tid < 128) *(float4*)&h_s[tid * 4] = zz;
            else if (tid < 192) *(float4*)&m_s[(tid - 128) * 4] = zz;
            if (tid < 16) up[tid] = 0.f;
            __syncthreads();
        } else {
            const uint tver = (uint)(layer * 1024 + t - 1);
            const ull* Hp = Hv + (size_t)(pp * 8 + b) * 512;
            const ull* Mp = Mv + (size_t)(pp * 8 + b) * 256;
            const ull* Up = Uv + (size_t)(pp * 8 + b) * 16;
            ull v0 = 0, v1 = 0, v2 = 0, v3 = 0;
            bool d0 = false, d1 = false, d2 = false, d3 = (tid >= 16);
            int guard = 0;
            while (guard++ < (1 << 24)) {
                if (!d0) { v0 = vload(&Hp[tid]);       d0 = ((uint)(v0 >> 32)) >= tver; }
                if (!d1) { v1 = vload(&Hp[tid + 256]); d1 = ((uint)(v1 >> 32)) >= tver; }
                if (!d2) { v2 = vload(&Mp[tid]);       d2 = ((uint)(v2 >> 32)) >= tver; }
                if (!d3) { v3 = vload(&Up[tid]);       d3 = ((uint)(v3 >> 32)) >= tver; }
                if (d0 && d1 && d2 && d3) break;
            }
            h_s[tid] = unpackv(v0);
            h_s[tid + 256] = unpackv(v1);
            m_s[tid] = unpackv(v2);
            if (tid < 16) up[tid] = unpackv(v3);
            __syncthreads();
        }
        float u = av;
#pragma unroll
        for (int i = 0; i < 16; i++) u += up[i];

        float a0 = 0.f, a1 = 0.f, a2 = 0.f, a3 = 0.f;
        {
            const float* hp = &h_s[s * 128];
#pragma unroll
            for (int k4 = 0; k4 < 32; k4++) {
                float4 hv = *(const float4*)&hp[k4 * 4];
                a0 += wh[k4 * 4 + 0] * hv.x; a1 += wh[k4 * 4 + 1] * hv.y;
                a2 += wh[k4 * 4 + 2] * hv.z; a3 += wh[k4 * 4 + 3] * hv.w;
            }
            const float* mp = &m_s[s * 64];
#pragma unroll
            for (int k4 = 0; k4 < 16; k4++) {
                float4 mv = *(const float4*)&mp[k4 * 4];
                a0 += wma[k4 * 4 + 0] * mv.x; a1 += wma[k4 * 4 + 1] * mv.y;
                a2 += wma[k4 * 4 + 2] * mv.z; a3 += wma[k4 * 4 + 3] * mv.w;
            }
        }
        float qa = (a0 + a1) + (a2 + a3);
        float z0 = 0.f, z1 = 0.f, z2 = 0.f, z3 = 0.f;
        {
            const float* ap = &A_lds[rz * 260 + sz * 32];
            const float* mp = &m_s[sz * 32];
#pragma unroll
            for (int k4 = 0; k4 < 8; k4++) {
                float4 avv = *(const float4*)&ap[k4 * 4];
                float4 mvv = *(const float4*)&mp[k4 * 4];
                z0 += avv.x * mvv.x; z1 += avv.y * mvv.y; z2 += avv.z * mvv.z; z3 += avv.w * mvv.w;
            }
        }
        float za = (z0 + z1) + (z2 + z3);
        red[r * 4 + s] = qa;
        red2[rz * 8 + sz] = za;
        __syncthreads();

        const uint wver = (uint)(layer * 1024 + t);
        float hn = 0.f, mn = 0.f;
        if (tid < 64) {
            float4 rv = *(const float4*)&red[tid * 4];
            float pre = cpre + u * wmb + (rv.x + rv.y) + (rv.z + rv.w);
            hn = tanh_fast(pre);
            vstore(&Hv[(size_t)(cp * 8 + b) * 512 + g * 64 + tid], packv(hn, wver));
            ysrow[(size_t)(t - 1) * 512 + tid] = hn;
            float pe = ehs[tid] * hn;
#pragma unroll
            for (int off = 32; off; off >>= 1) pe += __shfl_xor(pe, off, 64);
            if (tid == 0) vstore(&Uv[(size_t)(cp * 8 + b) * 16 + g], packv(pe, wver));
        } else if (tid < 96) {
            int i = tid - 64;
            float4 r0 = *(const float4*)&red2[i * 8];
            float4 r1 = *(const float4*)&red2[i * 8 + 4];
            mn = ((r0.x + r0.y) + (r0.z + r0.w)) + ((r1.x + r1.y) + (r1.z + r1.w)) + u * bdv;
            vstore(&Mv[(size_t)(cp * 8 + b) * 256 + g * 32 + i], packv(mn, wver));
            float pe = ems[i] * mn;
#pragma unroll
            for (int off = 16; off; off >>= 1) pe += __shfl_xor(pe, off, 64);
            if (i == 0) vstore(&Uv[(size_t)(cp * 8 + b) * 16 + 8 + g], packv(pe, wver));
        }
        if (t == 1024) {
            if (fl) {
                float* ob = (float*)outbase;
                if (tid < 64) ob[hsL + b * 512 + g * 64 + tid] = hn;
                else if (tid < 96) ob[msL + b * 256 + g * 32 + (tid - 64)] = mn;
            } else {
                ushort* ob = (ushort*)outbase;
                if (tid < 64) ob[hsL + b * 512 + g * 64 + tid] = f2bf(hn);
                else if (tid < 96) ob[msL + b * 256 + g * 32 + (tid - 64)] = f2bf(mn);
            }
        }
        __syncthreads();
    }
}

// ---------------- launch ---------------------------------------------------
extern "C" void kernel_launch(void* const* d_in, const int* in_sizes, int n_in,
                              void* d_out, int out_size, void* d_ws, size_t ws_size,
                              hipStream_t stream) {
    char* ws = (char*)d_ws;
    uint* flag = (uint*)(ws + OFF_FLAG);
    float* A_c = (float*)(ws + OFF_A);
    float* B_c = (float*)(ws + OFF_BD);
    float* apre = (float*)(ws + OFF_APRE);
    float* WmAb = (float*)(ws + OFF_WMA);
    ull* Hv = (ull*)(ws + OFF_HV);
    ull* Mv = (ull*)(ws + OFF_MV);
    ull* Uv = (ull*)(ws + OFF_UV);
    ushort* actb = (ushort*)(ws + OFF_ACTB);
    ushort* qb_ = (ushort*)(ws + OFF_Q);
    ushort* kb_ = (ushort*)(ws + OFF_KV);
    ushort* vb_ = (ushort*)(ws + OFF_KV + 8388608u);
    ushort* ctx = qb_;
    float* eo = (float*)(ws + OFF_KV);
    float* cbuf = eo;
    float* ysb = cbuf;
    double* Mm = (double*)(ws + OFF_KV);
    double* Tt = (double*)(ws + OFF_KV + 528640u);
    double* Pp = (double*)(ws + OFF_KV + 1057280u);

    k_sniff<<<1, 64, 0, stream>>>((const ushort*)d_in[0], flag);

    static const int isF32[23] = {0,0,0, 0,0,0,0,0,0,0,0, 0,0, 0,1,1, 0,1,1, 0,0,0,0};
    const void* cp[23];
    {
        size_t o16 = 0, o32 = 0;
        for (int i = 0; i < 23; i++) {
            int n = in_sizes[i];
            if (isF32[i]) {
                float* dst = (float*)(ws + OFF_B32 + o32 * 4);
                k_cvt32<<<(n + 255) / 256, 256, 0, stream>>>(d_in[i], dst, n, flag);
                cp[i] = dst;
                o32 += (size_t)((n + 127) & ~127);
            } else {
                ushort* dst = (ushort*)(ws + OFF_B16 + o16 * 2);
                k_cvt16<<<(n + 255) / 256, 256, 0, stream>>>(d_in[i], dst, n, flag);
                cp[i] = dst;
                o16 += (size_t)((n + 127) & ~127);
            }
        }
    }
    const ushort* xb    = (const ushort*)cp[0];
    const ushort* W_in  = (const ushort*)cp[1];
    const ushort* b_in  = (const ushort*)cp[2];
    const ushort* Wq    = (const ushort*)cp[3];
    const ushort* bq    = (const ushort*)cp[4];
    const ushort* Wk    = (const ushort*)cp[5];
    const ushort* bk    = (const ushort*)cp[6];
    const ushort* Wv    = (const ushort*)cp[7];
    const ushort* bv    = (const ushort*)cp[8];
    const ushort* Wo    = (const ushort*)cp[9];
    const ushort* bo    = (const ushort*)cp[10];
    const ushort* g_at  = (const ushort*)cp[11];
    const ushort* b_at  = (const ushort*)cp[12];
    const ushort* e_x   = (const ushort*)cp[13];
    const float*  e_h   = (const float*)cp[14];
    const float*  e_m   = (const float*)cp[15];
    const ushort* Wx    = (const ushort*)cp[16];
    const float*  Wh    = (const float*)cp[17];
    const float*  Wm    = (const float*)cp[18];
    const ushort* g_lnp = (const ushort*)cp[19];
    const ushort* b_lnp = (const ushort*)cp[20];
    const ushort* W_out = (const ushort*)cp[21];
    const ushort* b_out = (const ushort*)cp[22];

    k_expm_init<<<259, 256, 0, stream>>>(Mm, Tt, Hv);   // Hv|Mv|Uv contiguous
    double* cur = Tt; double* oth = Pp;
    for (int k = 20; k >= 1; k--) {
        k_expm_mul<<<259, 256, 0, stream>>>(Mm, cur, oth, k);
        std::swap(cur, oth);
    }
    for (int r = 0; r < 11; r++) {
        k_expm_mul<<<259, 256, 0, stream>>>(Mm, cur, oth, 0);
        std::swap(cur, oth);
    }
    k_expm_extract<<<256, 256, 0, stream>>>(cur, A_c, B_c);

    k_in_proj<<<16384, 256, 0, stream>>>(xb, W_in, b_in, actb);

    dim3 gg(8, 128);
    for (int L = 0; L < NLAYER; L++) {
        const size_t wofs = (size_t)L * 512 * 512;
        k_gemm<<<gg, 256, 0, stream>>>(actb, Wq + wofs, bq + L * 512, nullptr, qb_, 8192, 512, 512, nullptr);
        k_gemm<<<gg, 256, 0, stream>>>(actb, Wk + wofs, bk + L * 512, nullptr, kb_, 8192, 512, 512, nullptr);
        k_gemm<<<gg, 256, 0, stream>>>(actb, Wv + wofs, bv + L * 512, nullptr, vb_, 8192, 512, 512, nullptr);
        k_flash<<<dim3(16, 64), 256, 0, stream>>>(qb_, kb_, vb_, ctx);
        k_gemm<<<gg, 256, 0, stream>>>(ctx, Wo + wofs, bo + L * 512, eo, nullptr, 8192, 512, 512, nullptr);
        k_ln<<<2048, 256, 0, stream>>>(eo, actb, g_at + L * 512, b_at + L * 512, actb, 1);
        k_wma<<<dim3(512, 2), 256, 0, stream>>>(Wm + (size_t)L * 512 * 256, A_c, B_c, WmAb);
        k_apre<<<2048, 256, 0, stream>>>(actb, e_x + L * 512, apre);
        k_gemm<<<gg, 256, 0, stream>>>(actb, Wx + wofs, nullptr, cbuf, nullptr, 8192, 512, 512, nullptr);
        k_scan<<<64, 256, 0, stream>>>(Wh + wofs, WmAb, A_c, B_c,
                                       e_h + L * 512, e_m + L * 256,
                                       cbuf, apre, ysb,
                                       Hv, Mv, Uv,
                                       d_out, HS_OFF + L * 4096, MS_OFF + L * 2048,
                                       L, flag);
        k_ln<<<2048, 256, 0, stream>>>(ysb, actb, g_lnp + L * 512, b_lnp + L * 512, actb, 0);
    }
    k_gemm<<<gg, 256, 0, stream>>>(actb, W_out, b_out, (float*)d_out, (ushort*)d_out, 8192, 512, 512, flag);
}